// Round 1
// baseline (455.689 us; speedup 1.0000x reference)
//
#include <hip/hip_runtime.h>
#include <math.h>

#define NB 32
#define NC 3
#define HH 512
#define WW 512

// ---------- helpers ----------

// XOR swizzle for per-line LDS FFT: 2-way (free) bank conflicts on all 3 stages
__device__ __forceinline__ int swz(int i){ int h=(i>>6)&7; return i ^ (h<<3) ^ h; }
// base-8 digit reversal of 9-bit index
__device__ __forceinline__ int rev9(int k){ return ((k&7)<<6) | (k&56) | (k>>6); }

// sin/cos of 2*pi*x (x in revolutions, [0,1)) -> v_sin_f32/v_cos_f32
__device__ __forceinline__ float sin2pi(float x){
#if __has_builtin(__builtin_amdgcn_sinf)
  return __builtin_amdgcn_sinf(x);
#else
  return __sinf(6.28318530717958647692f*x);
#endif
}
__device__ __forceinline__ float cos2pi(float x){
#if __has_builtin(__builtin_amdgcn_cosf)
  return __builtin_amdgcn_cosf(x);
#else
  return __cosf(6.28318530717958647692f*x);
#endif
}

// unnormalized 8-point DFT. S=-1: forward (e^{-2pi i/8}); S=+1: conjugate (8*inverse)
template<int S>
__device__ __forceinline__ void dft8(float* xr, float* xi){
  const float r2 = 0.70710678118654752f;
  float tr[4], ti[4], mr[4], mi[4];
#pragma unroll
  for(int n=0;n<4;n++){
    tr[n]=xr[n]+xr[n+4]; ti[n]=xi[n]+xi[n+4];
    mr[n]=xr[n]-xr[n+4]; mi[n]=xi[n]-xi[n+4];
  }
  float or_[4], oi_[4];
  or_[0]=mr[0];               oi_[0]=mi[0];
  or_[1]=r2*(mr[1]-S*mi[1]);  oi_[1]=r2*(mi[1]+S*mr[1]);   // * (r2 + i S r2)
  or_[2]=-S*mi[2];            oi_[2]= S*mr[2];             // * (S i)
  or_[3]=-r2*(mr[3]+S*mi[3]); oi_[3]= r2*(S*mr[3]-mi[3]);  // * (-r2 + i S r2)
  float s0r=tr[0]+tr[2], s0i=ti[0]+ti[2];
  float s1r=tr[1]+tr[3], s1i=ti[1]+ti[3];
  float d0r=tr[0]-tr[2], d0i=ti[0]-ti[2];
  float d1r=tr[1]-tr[3], d1i=ti[1]-ti[3];
  xr[0]=s0r+s1r;   xi[0]=s0i+s1i;
  xr[4]=s0r-s1r;   xi[4]=s0i-s1i;
  xr[2]=d0r-S*d1i; xi[2]=d0i+S*d1r;
  xr[6]=d0r+S*d1i; xi[6]=d0i-S*d1r;
  float p0r=or_[0]+or_[2], p0i=oi_[0]+oi_[2];
  float p1r=or_[1]+or_[3], p1i=oi_[1]+oi_[3];
  float e0r=or_[0]-or_[2], e0i=oi_[0]-oi_[2];
  float e1r=or_[1]-or_[3], e1i=oi_[1]-oi_[3];
  xr[1]=p0r+p1r;   xi[1]=p0i+p1i;
  xr[5]=p0r-p1r;   xi[5]=p0i-p1i;
  xr[3]=e0r-S*e1i; xi[3]=e0i+S*e1r;
  xr[7]=e0r+S*e1i; xi[7]=e0i-S*e1r;
}

// multiply x[q] by exp(S*2*pi*i*n*q*invM), q=0..7 (q=0 is identity)
template<int S>
__device__ __forceinline__ void twid(float* xr, float* xi, int n, float invM){
  float f = (float)n * invM;
  float c1 = cos2pi(f), s1 = (float)S * sin2pi(f);
  float cr=c1, ci=s1;
#pragma unroll
  for(int q=1;q<8;q++){
    float a=xr[q], b=xi[q];
    xr[q]=a*cr-b*ci; xi[q]=a*ci+b*cr;
    float nr=cr*c1-ci*s1, ni=cr*s1+ci*c1;
    cr=nr; ci=ni;
  }
}

// ---------- K1: row FFT (real -> complex, natural -> digit-reversed q) ----------
// one wave per line; stage 0 straight from coalesced global loads; output 64B/lane contiguous
__global__ __launch_bounds__(256) void k_row_fft(const float* __restrict__ xc, float2* __restrict__ Fc){
  __shared__ float lre[4][512];
  __shared__ float lim[4][512];
  const int wv = threadIdx.x>>6, t = threadIdx.x&63;
  const int line = blockIdx.x*4 + wv;           // b*512 + h within channel
  const int b = line>>9, h = line&511;
  const float* src = xc + (size_t)b*(NC*HH*WW) + (size_t)h*WW;
  float2* dst = Fc + (size_t)line*WW;
  float xr[8], xi[8];
#pragma unroll
  for(int i=0;i<8;i++){ xr[i]=src[t+64*i]; xi[i]=0.f; }
  dft8<-1>(xr,xi);
  twid<-1>(xr,xi,t,1.0f/512.0f);
#pragma unroll
  for(int q=0;q<8;q++){ int p=swz(t+64*q); lre[wv][p]=xr[q]; lim[wv][p]=xi[q]; }
  __syncthreads();
  const int beta=t>>3, n1=t&7, base1=64*beta+n1;
#pragma unroll
  for(int i=0;i<8;i++){ int p=swz(base1+8*i); xr[i]=lre[wv][p]; xi[i]=lim[wv][p]; }
  dft8<-1>(xr,xi);
  twid<-1>(xr,xi,n1,1.0f/64.0f);
#pragma unroll
  for(int q=0;q<8;q++){ int p=swz(base1+8*q); lre[wv][p]=xr[q]; lim[wv][p]=xi[q]; }
  __syncthreads();
#pragma unroll
  for(int i=0;i<8;i++){ int p=swz(8*t+i); xr[i]=lre[wv][p]; xi[i]=lim[wv][p]; }
  dft8<-1>(xr,xi);
  float4* d4 = (float4*)(dst + 8*t);
  d4[0]=make_float4(xr[0],xi[0],xr[1],xi[1]);
  d4[1]=make_float4(xr[2],xi[2],xr[3],xi[3]);
  d4[2]=make_float4(xr[4],xi[4],xr[5],xi[5]);
  d4[3]=make_float4(xr[6],xi[6],xr[7],xi[7]);
}

// ---------- K2: column FFT over h (in-place, tile of 16 columns in LDS, stride-17 pad) ----------
__global__ __launch_bounds__(256) void k_col_fft(float2* __restrict__ Fc){
  __shared__ float sre[512*17];
  __shared__ float sim[512*17];
  const int b  = blockIdx.x>>5;
  const int q0 = (blockIdx.x&31)*16;
  float2* base = Fc + (size_t)b*HH*WW + q0;
  const int c = threadIdx.x&15, w = threadIdx.x>>4;
#pragma unroll
  for(int k=0;k<32;k++){
    int f = threadIdx.x + 256*k;
    int r = f>>4, col = f&15;
    float2 v = base[(size_t)r*WW + col];
    sre[r*17+col]=v.x; sim[r*17+col]=v.y;
  }
  __syncthreads();
#pragma unroll
  for(int jj=0;jj<4;jj++){                      // stage 0
    int n = jj*16 + w;
    float xr[8], xi[8];
#pragma unroll
    for(int i=0;i<8;i++){ int e=n+64*i; xr[i]=sre[e*17+c]; xi[i]=sim[e*17+c]; }
    dft8<-1>(xr,xi);
    twid<-1>(xr,xi,n,1.0f/512.0f);
#pragma unroll
    for(int q=0;q<8;q++){ int e=n+64*q; sre[e*17+c]=xr[q]; sim[e*17+c]=xi[q]; }
  }
  __syncthreads();
#pragma unroll
  for(int jj=0;jj<4;jj++){                      // stage 1
    int m = jj*16 + w;
    int bb = m>>3, nn = m&7, bs = 64*bb+nn;
    float xr[8], xi[8];
#pragma unroll
    for(int i=0;i<8;i++){ int e=bs+8*i; xr[i]=sre[e*17+c]; xi[i]=sim[e*17+c]; }
    dft8<-1>(xr,xi);
    twid<-1>(xr,xi,nn,1.0f/64.0f);
#pragma unroll
    for(int q=0;q<8;q++){ int e=bs+8*q; sre[e*17+c]=xr[q]; sim[e*17+c]=xi[q]; }
  }
  __syncthreads();
#pragma unroll
  for(int jj=0;jj<4;jj++){                      // stage 2 (no twiddle)
    int m = jj*16+w;
    float xr[8], xi[8];
#pragma unroll
    for(int i=0;i<8;i++){ int e=8*m+i; xr[i]=sre[e*17+c]; xi[i]=sim[e*17+c]; }
    dft8<-1>(xr,xi);
#pragma unroll
    for(int q=0;q<8;q++){ int e=8*m+q; sre[e*17+c]=xr[q]; sim[e*17+c]=xi[q]; }
  }
  __syncthreads();
#pragma unroll
  for(int k=0;k<32;k++){
    int f=threadIdx.x+256*k;
    int r=f>>4, col=f&15;
    base[(size_t)r*WW+col]=make_float2(sre[r*17+col], sim[r*17+col]);
  }
}

// ---------- K3: sum(running_amp) for the ==0 branch ----------
__global__ __launch_bounds__(256) void k_rsum(const float* __restrict__ ra, float* __restrict__ out, int n){
  float s=0.f;
  for(int i=blockIdx.x*256+threadIdx.x; i<n; i+=gridDim.x*256) s+=ra[i];
#pragma unroll
  for(int off=32;off>=1;off>>=1) s += __shfl_down(s, off, 64);
  if((threadIdx.x&63)==0) atomicAdd(out, s);
}

// ---------- K4: batch-mean |F| + EMA with running_amp (gather via rev9 + fftshift) ----------
__global__ __launch_bounds__(256) void k_ema(const float2* __restrict__ Fc, const float* __restrict__ rac,
                                             const float* __restrict__ rsum, float* __restrict__ newamp){
  int f = blockIdx.x*256 + threadIdx.x;         // 0 .. 512*512-1
  int p = f>>9, q = f&511;                      // digit-reversed coords
  float s=0.f;
#pragma unroll 4
  for(int b=0;b<NB;b++){
    float2 v = Fc[((size_t)b*HH + p)*WW + q];
    s += sqrtf(v.x*v.x+v.y*v.y);
  }
  float mean = s*(1.0f/32.0f);
  int hs=(rev9(p)+256)&511, ws2=(rev9(q)+256)&511;
  float ra = rac[hs*WW+ws2];
  float nv = (rsum[0]==0.0f) ? mean : (0.9f*ra + 0.1f*mean);
  newamp[f]=nv;
}

// ---------- K5: scale (magnitude substitution, keep phase, fold 1/N^2) + column IFFT ----------
__global__ __launch_bounds__(256) void k_col_ifft(float2* __restrict__ Fc, const float* __restrict__ newamp){
  __shared__ float sre[512*17];
  __shared__ float sim[512*17];
  const int b  = blockIdx.x>>5;
  const int q0 = (blockIdx.x&31)*16;
  float2* base = Fc + (size_t)b*HH*WW + q0;
  const float* na = newamp + q0;
  const int c = threadIdx.x&15, w = threadIdx.x>>4;
  const float invN2 = 1.0f/262144.0f;
#pragma unroll
  for(int k=0;k<32;k++){
    int f=threadIdx.x+256*k;
    int r=f>>4, col=f&15;
    float2 v = base[(size_t)r*WW+col];
    float amp = na[(size_t)r*WW+col];
    float mag = sqrtf(v.x*v.x + v.y*v.y);
    float fr, fi;
    if(mag > 0.f){ float sc = amp*invN2/mag; fr=v.x*sc; fi=v.y*sc; }
    else         { fr = amp*invN2; fi=0.f; }              // angle(0)=0 -> exp(i*0)=1
    sre[r*17+col]=fr; sim[r*17+col]=fi;
  }
  __syncthreads();
#pragma unroll
  for(int jj=0;jj<4;jj++){                      // inverse of stage 2
    int m = jj*16+w;
    float xr[8], xi[8];
#pragma unroll
    for(int q=0;q<8;q++){ int e=8*m+q; xr[q]=sre[e*17+c]; xi[q]=sim[e*17+c]; }
    dft8<1>(xr,xi);
#pragma unroll
    for(int i=0;i<8;i++){ int e=8*m+i; sre[e*17+c]=xr[i]; sim[e*17+c]=xi[i]; }
  }
  __syncthreads();
#pragma unroll
  for(int jj=0;jj<4;jj++){                      // inverse of stage 1
    int m = jj*16 + w;
    int bb = m>>3, nn = m&7, bs = 64*bb+nn;
    float xr[8], xi[8];
#pragma unroll
    for(int q=0;q<8;q++){ int e=bs+8*q; xr[q]=sre[e*17+c]; xi[q]=sim[e*17+c]; }
    twid<1>(xr,xi,nn,1.0f/64.0f);
    dft8<1>(xr,xi);
#pragma unroll
    for(int i=0;i<8;i++){ int e=bs+8*i; sre[e*17+c]=xr[i]; sim[e*17+c]=xi[i]; }
  }
  __syncthreads();
#pragma unroll
  for(int jj=0;jj<4;jj++){                      // inverse of stage 0 -> natural h
    int n = jj*16+w;
    float xr[8], xi[8];
#pragma unroll
    for(int q=0;q<8;q++){ int e=n+64*q; xr[q]=sre[e*17+c]; xi[q]=sim[e*17+c]; }
    twid<1>(xr,xi,n,1.0f/512.0f);
    dft8<1>(xr,xi);
#pragma unroll
    for(int i=0;i<8;i++){ int e=n+64*i; sre[e*17+c]=xr[i]; sim[e*17+c]=xi[i]; }
  }
  __syncthreads();
#pragma unroll
  for(int k=0;k<32;k++){
    int f=threadIdx.x+256*k;
    int r=f>>4, col=f&15;
    base[(size_t)r*WW+col]=make_float2(sre[r*17+col], sim[r*17+col]);
  }
}

// ---------- K6: row IFFT (digit-reversed q in -> natural w out, write real part) ----------
__global__ __launch_bounds__(256) void k_row_ifft(const float2* __restrict__ Fc, float* __restrict__ outc){
  __shared__ float lre[4][512];
  __shared__ float lim[4][512];
  const int wv=threadIdx.x>>6, t=threadIdx.x&63;
  const int line = blockIdx.x*4+wv;
  const int b=line>>9, h=line&511;
  const float2* src = Fc + (size_t)line*WW;
  float* dst = outc + (size_t)b*(NC*HH*WW) + (size_t)h*WW;
  float xr[8], xi[8];
  const float4* s4=(const float4*)(src+8*t);
  float4 v0=s4[0], v1=s4[1], v2=s4[2], v3=s4[3];
  xr[0]=v0.x; xi[0]=v0.y; xr[1]=v0.z; xi[1]=v0.w;
  xr[2]=v1.x; xi[2]=v1.y; xr[3]=v1.z; xi[3]=v1.w;
  xr[4]=v2.x; xi[4]=v2.y; xr[5]=v2.z; xi[5]=v2.w;
  xr[6]=v3.x; xi[6]=v3.y; xr[7]=v3.z; xi[7]=v3.w;
  dft8<1>(xr,xi);                               // inverse of stage 2
#pragma unroll
  for(int i=0;i<8;i++){ int p=swz(8*t+i); lre[wv][p]=xr[i]; lim[wv][p]=xi[i]; }
  __syncthreads();
  const int beta=t>>3, n1=t&7, base1=64*beta+n1;
#pragma unroll
  for(int q=0;q<8;q++){ int p=swz(base1+8*q); xr[q]=lre[wv][p]; xi[q]=lim[wv][p]; }
  twid<1>(xr,xi,n1,1.0f/64.0f);
  dft8<1>(xr,xi);                               // inverse of stage 1
#pragma unroll
  for(int i=0;i<8;i++){ int p=swz(base1+8*i); lre[wv][p]=xr[i]; lim[wv][p]=xi[i]; }
  __syncthreads();
#pragma unroll
  for(int q=0;q<8;q++){ int p=swz(t+64*q); xr[q]=lre[wv][p]; xi[q]=lim[wv][p]; }
  twid<1>(xr,xi,t,1.0f/512.0f);
  dft8<1>(xr,xi);                               // inverse of stage 0 -> natural w
#pragma unroll
  for(int i=0;i<8;i++){ dst[t+64*i]=xr[i]; }
}

// ---------- launch ----------
extern "C" void kernel_launch(void* const* d_in, const int* in_sizes, int n_in,
                              void* d_out, int out_size, void* d_ws, size_t ws_size,
                              hipStream_t stream) {
  const float* x  = (const float*)d_in[0];        // [32,3,512,512]
  const float* ra = (const float*)d_in[1];        // [3,512,512]
  float* out = (float*)d_out;

  const size_t fbytes  = (size_t)NB*HH*WW*sizeof(float2);   // 67.1 MB per channel
  const size_t nabytes = (size_t)HH*WW*sizeof(float);       // 1 MB
  if (ws_size < fbytes + nabytes + 64) return;              // clean failure if ws too small

  float2* F      = (float2*)d_ws;
  float*  newamp = (float*)((char*)d_ws + fbytes);
  float*  rsum   = (float*)((char*)d_ws + fbytes + nabytes);

  hipMemsetAsync(rsum, 0, sizeof(float), stream);
  k_rsum<<<768,256,0,stream>>>(ra, rsum, NC*HH*WW);

  for(int c=0;c<NC;c++){
    const float* xc  = x   + (size_t)c*HH*WW;
    const float* rac = ra  + (size_t)c*HH*WW;
    float*       oc  = out + (size_t)c*HH*WW;
    k_row_fft <<<NB*HH/4, 256, 0, stream>>>(xc, F);
    k_col_fft <<<NB*32,   256, 0, stream>>>(F);
    k_ema     <<<HH*WW/256,256,0, stream>>>(F, rac, rsum, newamp);
    k_col_ifft<<<NB*32,   256, 0, stream>>>(F, newamp);
    k_row_ifft<<<NB*HH/4, 256, 0, stream>>>(F, oc);
  }
}

// Round 3
// 342.163 us; speedup vs baseline: 1.3318x; 1.3318x over previous
//
#include <hip/hip_runtime.h>
#include <math.h>

#define NB 32
#define NC 3
#define HH 512
#define WW 512
#define W2 272   // padded half-spectrum width: cols 0..256 valid, 257..271 pad

// ---------- helpers ----------

// XOR swizzle for per-line LDS FFT: 2-way (free) bank conflicts on all 3 stages
__device__ __forceinline__ int swz(int i){ int h=(i>>6)&7; return i ^ (h<<3) ^ h; }
// base-8 digit reversal of 9-bit index
__device__ __forceinline__ int rev9(int k){ return ((k&7)<<6) | (k&56) | (k>>6); }

__device__ __forceinline__ float sin2pi(float x){
#if __has_builtin(__builtin_amdgcn_sinf)
  return __builtin_amdgcn_sinf(x);
#else
  return __sinf(6.28318530717958647692f*x);
#endif
}
__device__ __forceinline__ float cos2pi(float x){
#if __has_builtin(__builtin_amdgcn_cosf)
  return __builtin_amdgcn_cosf(x);
#else
  return __cosf(6.28318530717958647692f*x);
#endif
}

// unnormalized 8-point DFT. S=-1: forward; S=+1: conjugate (8*inverse)
template<int S>
__device__ __forceinline__ void dft8(float* xr, float* xi){
  const float r2 = 0.70710678118654752f;
  float tr[4], ti[4], mr[4], mi[4];
#pragma unroll
  for(int n=0;n<4;n++){
    tr[n]=xr[n]+xr[n+4]; ti[n]=xi[n]+xi[n+4];
    mr[n]=xr[n]-xr[n+4]; mi[n]=xi[n]-xi[n+4];
  }
  float or_[4], oi_[4];
  or_[0]=mr[0];               oi_[0]=mi[0];
  or_[1]=r2*(mr[1]-S*mi[1]);  oi_[1]=r2*(mi[1]+S*mr[1]);
  or_[2]=-S*mi[2];            oi_[2]= S*mr[2];
  or_[3]=-r2*(mr[3]+S*mi[3]); oi_[3]= r2*(S*mr[3]-mi[3]);
  float s0r=tr[0]+tr[2], s0i=ti[0]+ti[2];
  float s1r=tr[1]+tr[3], s1i=ti[1]+ti[3];
  float d0r=tr[0]-tr[2], d0i=ti[0]-ti[2];
  float d1r=tr[1]-tr[3], d1i=ti[1]-ti[3];
  xr[0]=s0r+s1r;   xi[0]=s0i+s1i;
  xr[4]=s0r-s1r;   xi[4]=s0i-s1i;
  xr[2]=d0r-S*d1i; xi[2]=d0i+S*d1r;
  xr[6]=d0r+S*d1i; xi[6]=d0i-S*d1r;
  float p0r=or_[0]+or_[2], p0i=oi_[0]+oi_[2];
  float p1r=or_[1]+or_[3], p1i=oi_[1]+oi_[3];
  float e0r=or_[0]-or_[2], e0i=oi_[0]-oi_[2];
  float e1r=or_[1]-or_[3], e1i=oi_[1]-oi_[3];
  xr[1]=p0r+p1r;   xi[1]=p0i+p1i;
  xr[5]=p0r-p1r;   xi[5]=p0i-p1i;
  xr[3]=e0r-S*e1i; xi[3]=e0i+S*e1r;
  xr[7]=e0r+S*e1i; xi[7]=e0i-S*e1r;
}

template<int S>
__device__ __forceinline__ void twid(float* xr, float* xi, int n, float invM){
  float f = (float)n * invM;
  float c1 = cos2pi(f), s1 = (float)S * sin2pi(f);
  float cr=c1, ci=s1;
#pragma unroll
  for(int q=1;q<8;q++){
    float a=xr[q], b=xi[q];
    xr[q]=a*cr-b*ci; xi[q]=a*ci+b*cr;
    float nr=cr*c1-ci*s1, ni=cr*s1+ci*c1;
    cr=nr; ci=ni;
  }
}

// ---------- K1: paired-row real FFT -> half spectrum (natural w, 0..256) ----------
// one wave per row-pair (2r, 2r+1): z = a + i*b, 512-pt DIF FFT, Hermitian unpack
__global__ __launch_bounds__(256) void k_row_rfft(const float* __restrict__ xc, float2* __restrict__ Fh){
  __shared__ float lre[4][512];
  __shared__ float lim[4][512];
  const int wv = threadIdx.x>>6, t = threadIdx.x&63;
  const int pr = blockIdx.x*4 + wv;             // pair index: b*256 + r2
  const int b = pr>>8, r2 = pr&255;
  const float* sa = xc + (size_t)b*(NC*HH*WW) + (size_t)(2*r2)*WW;
  const float* sb = sa + WW;
  float xr[8], xi[8];
#pragma unroll
  for(int i=0;i<8;i++){ xr[i]=sa[t+64*i]; xi[i]=sb[t+64*i]; }
  dft8<-1>(xr,xi);
  twid<-1>(xr,xi,t,1.0f/512.0f);
#pragma unroll
  for(int q=0;q<8;q++){ int p=swz(t+64*q); lre[wv][p]=xr[q]; lim[wv][p]=xi[q]; }
  __syncthreads();
  const int beta=t>>3, n1=t&7, base1=64*beta+n1;
#pragma unroll
  for(int i=0;i<8;i++){ int p=swz(base1+8*i); xr[i]=lre[wv][p]; xi[i]=lim[wv][p]; }
  dft8<-1>(xr,xi);
  twid<-1>(xr,xi,n1,1.0f/64.0f);
#pragma unroll
  for(int q=0;q<8;q++){ int p=swz(base1+8*q); lre[wv][p]=xr[q]; lim[wv][p]=xi[q]; }
  __syncthreads();
#pragma unroll
  for(int i=0;i<8;i++){ int p=swz(8*t+i); xr[i]=lre[wv][p]; xi[i]=lim[wv][p]; }
  dft8<-1>(xr,xi);
  // scatter to natural order: slot 8t+i holds Z[rev9(8t+i)]
  __syncthreads();
#pragma unroll
  for(int i=0;i<8;i++){ int nat = 64*i + 8*(t&7) + (t>>3); lre[wv][nat]=xr[i]; lim[wv][nat]=xi[i]; }
  __syncthreads();
  // Hermitian unpack: Ra[w]=(Z[w]+conj(Z[-w]))/2, Rb[w]=-i(Z[w]-conj(Z[-w]))/2
  float2* Fa = Fh + (size_t)(b*HH + 2*r2)*W2;
  float2* Fb = Fa + W2;
#pragma unroll
  for(int j=0;j<5;j++){
    int w = t + 64*j;
    if(w<=256){
      int m = (512-w)&511;
      float pr_=lre[wv][w], pi_=lim[wv][w], qr=lre[wv][m], qi=lim[wv][m];
      Fa[w]=make_float2(0.5f*(pr_+qr), 0.5f*(pi_-qi));
      Fb[w]=make_float2(0.5f*(pi_+qi), 0.5f*(qr-pr_));
    }
  }
}

// ---------- K2: column FFT over h on half spectrum (natural h in -> digit-rev h out) ----------
__global__ __launch_bounds__(256) void k_col_fft(float2* __restrict__ Fh){
  __shared__ float sre[512*17];
  __shared__ float sim[512*17];
  const int b    = blockIdx.x/17;
  const int tile = blockIdx.x - b*17;
  const int w0   = tile*16;
  float2* base = Fh + (size_t)b*HH*W2 + w0;
  const int c = threadIdx.x&15, w = threadIdx.x>>4;
#pragma unroll
  for(int k=0;k<32;k++){
    int f = threadIdx.x + 256*k;
    int r = f>>4, col = f&15;
    float2 v = base[(size_t)r*W2 + col];
    sre[r*17+col]=v.x; sim[r*17+col]=v.y;
  }
  __syncthreads();
#pragma unroll
  for(int jj=0;jj<4;jj++){                      // stage 0
    int n = jj*16 + w;
    float xr[8], xi[8];
#pragma unroll
    for(int i=0;i<8;i++){ int e=n+64*i; xr[i]=sre[e*17+c]; xi[i]=sim[e*17+c]; }
    dft8<-1>(xr,xi);
    twid<-1>(xr,xi,n,1.0f/512.0f);
#pragma unroll
    for(int q=0;q<8;q++){ int e=n+64*q; sre[e*17+c]=xr[q]; sim[e*17+c]=xi[q]; }
  }
  __syncthreads();
#pragma unroll
  for(int jj=0;jj<4;jj++){                      // stage 1
    int m = jj*16 + w;
    int bb = m>>3, nn = m&7, bs = 64*bb+nn;
    float xr[8], xi[8];
#pragma unroll
    for(int i=0;i<8;i++){ int e=bs+8*i; xr[i]=sre[e*17+c]; xi[i]=sim[e*17+c]; }
    dft8<-1>(xr,xi);
    twid<-1>(xr,xi,nn,1.0f/64.0f);
#pragma unroll
    for(int q=0;q<8;q++){ int e=bs+8*q; sre[e*17+c]=xr[q]; sim[e*17+c]=xi[q]; }
  }
  __syncthreads();
#pragma unroll
  for(int jj=0;jj<4;jj++){                      // stage 2 (no twiddle)
    int m = jj*16+w;
    float xr[8], xi[8];
#pragma unroll
    for(int i=0;i<8;i++){ int e=8*m+i; xr[i]=sre[e*17+c]; xi[i]=sim[e*17+c]; }
    dft8<-1>(xr,xi);
#pragma unroll
    for(int q=0;q<8;q++){ int e=8*m+q; sre[e*17+c]=xr[q]; sim[e*17+c]=xi[q]; }
  }
  __syncthreads();
#pragma unroll
  for(int k=0;k<32;k++){
    int f=threadIdx.x+256*k;
    int r=f>>4, col=f&15;
    if(w0+col<=256)
      base[(size_t)r*W2+col]=make_float2(sre[r*17+col], sim[r*17+col]);
  }
}

// ---------- K3: sum(running_amp) ----------
__global__ __launch_bounds__(256) void k_rsum(const float* __restrict__ ra, float* __restrict__ out, int n){
  float s=0.f;
  for(int i=blockIdx.x*256+threadIdx.x; i<n; i+=gridDim.x*256) s+=ra[i];
#pragma unroll
  for(int off=32;off>=1;off>>=1) s += __shfl_down(s, off, 64);
  if((threadIdx.x&63)==0) atomicAdd(out, s);
}

// ---------- K4: batch-mean |F| + symmetrized EMA amplitude A ----------
// Effective Hermitian amplitude: A_sym[h,w] = (A[h,w]+A[-h,-w])/2 with A=ifftshift(new_amp)
// EMA branch: 0.45*(ra[hs,ws]+ra[hs2,ws2]) + 0.1*mean|F|[h,w]; init branch: mean|F|[h,w]
__global__ __launch_bounds__(256) void k_amp(const float2* __restrict__ Fh, const float* __restrict__ rac,
                                             const float* __restrict__ rsum, float* __restrict__ A){
  int f = blockIdx.x*256 + threadIdx.x;         // 0 .. 512*272-1
  int p = f/W2, w = f - p*W2;                   // p = digit-rev h slot, w natural
  float s=0.f;
#pragma unroll 4
  for(int b=0;b<NB;b++){
    float2 v = Fh[((size_t)b*HH + p)*W2 + w];
    s += sqrtf(v.x*v.x+v.y*v.y);
  }
  float mean = s*(1.0f/32.0f);
  int h = rev9(p);
  int hs =(h+256)&511, ws =(w+256)&511;
  int hs2=(256-h)&511, ws2=(256-w)&511;
  float a_ = (rsum[0]==0.0f) ? mean
           : 0.45f*(rac[hs*WW+ws] + rac[hs2*WW+ws2]) + 0.1f*mean;
  A[f]=a_;
}

// ---------- K5: magnitude substitution + column IFFT (digit-rev h in -> natural h out) ----------
__global__ __launch_bounds__(256) void k_col_ifft(float2* __restrict__ Fh, const float* __restrict__ A){
  __shared__ float sre[512*17];
  __shared__ float sim[512*17];
  const int b    = blockIdx.x/17;
  const int tile = blockIdx.x - b*17;
  const int w0   = tile*16;
  float2* base = Fh + (size_t)b*HH*W2 + w0;
  const float* Aa = A + w0;
  const int c = threadIdx.x&15, w = threadIdx.x>>4;
  const float invN2 = 1.0f/262144.0f;
#pragma unroll
  for(int k=0;k<32;k++){
    int f=threadIdx.x+256*k;
    int r=f>>4, col=f&15;
    float2 v = base[(size_t)r*W2+col];
    float amp = Aa[(size_t)r*W2+col];
    float mag = sqrtf(v.x*v.x + v.y*v.y);
    float fr, fi;
    if(mag > 0.f){ float sc = amp*invN2/mag; fr=v.x*sc; fi=v.y*sc; }
    else         { fr = amp*invN2; fi=0.f; }
    sre[r*17+col]=fr; sim[r*17+col]=fi;
  }
  __syncthreads();
#pragma unroll
  for(int jj=0;jj<4;jj++){                      // inverse of stage 2
    int m = jj*16+w;
    float xr[8], xi[8];
#pragma unroll
    for(int q=0;q<8;q++){ int e=8*m+q; xr[q]=sre[e*17+c]; xi[q]=sim[e*17+c]; }
    dft8<1>(xr,xi);
#pragma unroll
    for(int i=0;i<8;i++){ int e=8*m+i; sre[e*17+c]=xr[i]; sim[e*17+c]=xi[i]; }
  }
  __syncthreads();
#pragma unroll
  for(int jj=0;jj<4;jj++){                      // inverse of stage 1
    int m = jj*16 + w;
    int bb = m>>3, nn = m&7, bs = 64*bb+nn;
    float xr[8], xi[8];
#pragma unroll
    for(int q=0;q<8;q++){ int e=bs+8*q; xr[q]=sre[e*17+c]; xi[q]=sim[e*17+c]; }
    twid<1>(xr,xi,nn,1.0f/64.0f);
    dft8<1>(xr,xi);
#pragma unroll
    for(int i=0;i<8;i++){ int e=bs+8*i; sre[e*17+c]=xr[i]; sim[e*17+c]=xi[i]; }
  }
  __syncthreads();
#pragma unroll
  for(int jj=0;jj<4;jj++){                      // inverse of stage 0 -> natural h
    int n = jj*16+w;
    float xr[8], xi[8];
#pragma unroll
    for(int q=0;q<8;q++){ int e=n+64*q; xr[q]=sre[e*17+c]; xi[q]=sim[e*17+c]; }
    twid<1>(xr,xi,n,1.0f/512.0f);
    dft8<1>(xr,xi);
#pragma unroll
    for(int i=0;i<8;i++){ int e=n+64*i; sre[e*17+c]=xr[i]; sim[e*17+c]=xi[i]; }
  }
  __syncthreads();
#pragma unroll
  for(int k=0;k<32;k++){
    int f=threadIdx.x+256*k;
    int r=f>>4, col=f&15;
    if(w0+col<=256)
      base[(size_t)r*W2+col]=make_float2(sre[r*17+col], sim[r*17+col]);
  }
}

// ---------- K6: paired-row inverse real FFT ----------
// After the column inverse, each row Y[h,.] is Hermitian along w: Y[h,512-w]=conj(Y[h,w]).
// So pair ADJACENT rows (2r, 2r+1): Z = rowA + i*rowB, each row's tail reconstructed
// from ITSELF: Z[w>256] = conj(A[m]) + i*conj(B[m]), m=512-w.
// Inverse 512-pt FFT -> out row 2r = Re(z), row 2r+1 = Im(z).
__global__ __launch_bounds__(256) void k_row_irfft(const float2* __restrict__ Fh, float* __restrict__ outc){
  __shared__ float gAr[4][264], gAi[4][264], gBr[4][264], gBi[4][264];
  __shared__ float lre[4][512], lim[4][512];
  const int wv=threadIdx.x>>6, t=threadIdx.x&63;
  const int pr = blockIdx.x*4+wv;               // b*256 + r2
  const int b = pr>>8, r2 = pr&255;
  const float2* Rp = Fh + (size_t)(b*HH + 2*r2)*W2;
  const float2* Rq = Rp + W2;
#pragma unroll
  for(int j=0;j<5;j++){
    int w = t + 64*j;
    if(w<=256){
      float2 v = Rp[w]; gAr[wv][w]=v.x; gAi[wv][w]=v.y;
      float2 u = Rq[w]; gBr[wv][w]=u.x; gBi[wv][w]=u.y;
    }
  }
  __syncthreads();
  // gather digit-reversed slots: slot 8t+i needs Z[rev9(8t+i)]
  float xr[8], xi[8];
#pragma unroll
  for(int i=0;i<8;i++){
    int w = rev9(8*t+i);
    float zr, zi;
    if(w<=256){ zr = gAr[wv][w]-gBi[wv][w]; zi = gAi[wv][w]+gBr[wv][w]; }
    else{
      int m = 512-w;   // row-wise Hermitian: Z[w] = conj(A[m]) + i*conj(B[m])
      zr = gAr[wv][m]+gBi[wv][m]; zi = gBr[wv][m]-gAi[wv][m];
    }
    xr[i]=zr; xi[i]=zi;
  }
  dft8<1>(xr,xi);                               // inverse of stage 2
#pragma unroll
  for(int i=0;i<8;i++){ int pp=swz(8*t+i); lre[wv][pp]=xr[i]; lim[wv][pp]=xi[i]; }
  __syncthreads();
  const int beta=t>>3, n1=t&7, base1=64*beta+n1;
#pragma unroll
  for(int qq=0;qq<8;qq++){ int pp=swz(base1+8*qq); xr[qq]=lre[wv][pp]; xi[qq]=lim[wv][pp]; }
  twid<1>(xr,xi,n1,1.0f/64.0f);
  dft8<1>(xr,xi);                               // inverse of stage 1
#pragma unroll
  for(int i=0;i<8;i++){ int pp=swz(base1+8*i); lre[wv][pp]=xr[i]; lim[wv][pp]=xi[i]; }
  __syncthreads();
#pragma unroll
  for(int qq=0;qq<8;qq++){ int pp=swz(t+64*qq); xr[qq]=lre[wv][pp]; xi[qq]=lim[wv][pp]; }
  twid<1>(xr,xi,t,1.0f/512.0f);
  dft8<1>(xr,xi);                               // inverse of stage 0 -> natural w
  float* oa = outc + (size_t)b*(NC*HH*WW) + (size_t)(2*r2)*WW;
  float* ob = oa + WW;
#pragma unroll
  for(int i=0;i<8;i++){ oa[t+64*i]=xr[i]; ob[t+64*i]=xi[i]; }
}

// ---------- launch ----------
extern "C" void kernel_launch(void* const* d_in, const int* in_sizes, int n_in,
                              void* d_out, int out_size, void* d_ws, size_t ws_size,
                              hipStream_t stream) {
  const float* x  = (const float*)d_in[0];        // [32,3,512,512]
  const float* ra = (const float*)d_in[1];        // [3,512,512]
  float* out = (float*)d_out;

  const size_t fbytes = (size_t)NB*HH*W2*sizeof(float2);   // 35.65 MB
  const size_t abytes = (size_t)HH*W2*sizeof(float);       // 0.56 MB
  if (ws_size < fbytes + abytes + 64) return;

  float2* Fh   = (float2*)d_ws;
  float*  A    = (float*)((char*)d_ws + fbytes);
  float*  rsum = (float*)((char*)d_ws + fbytes + abytes);

  hipMemsetAsync(rsum, 0, sizeof(float), stream);
  k_rsum<<<768,256,0,stream>>>(ra, rsum, NC*HH*WW);

  for(int c=0;c<NC;c++){
    const float* xc  = x   + (size_t)c*HH*WW;
    const float* rac = ra  + (size_t)c*HH*WW;
    float*       oc  = out + (size_t)c*HH*WW;
    k_row_rfft <<<NB*256/4, 256, 0, stream>>>(xc, Fh);
    k_col_fft  <<<NB*17,    256, 0, stream>>>(Fh);
    k_amp      <<<HH*W2/256,256, 0, stream>>>(Fh, rac, rsum, A);
    k_col_ifft <<<NB*17,    256, 0, stream>>>(Fh, A);
    k_row_irfft<<<NB*256/4, 256, 0, stream>>>(Fh, oc);
  }
}

// Round 4
// 241.612 us; speedup vs baseline: 1.8860x; 1.4162x over previous
//
#include <hip/hip_runtime.h>
#include <math.h>

#define NB 32
#define NC 3
#define HH 512
#define WW 512
#define W2 272   // padded half-spectrum width: cols 0..256 valid, 257..271 pad

// ---------- helpers ----------

// XOR swizzle for per-line LDS FFT: 2-way (free) bank conflicts on all 3 stages
__device__ __forceinline__ int swz(int i){ int h=(i>>6)&7; return i ^ (h<<3) ^ h; }
// base-8 digit reversal of 9-bit index
__device__ __forceinline__ int rev9(int k){ return ((k&7)<<6) | (k&56) | (k>>6); }

__device__ __forceinline__ float sin2pi(float x){
#if __has_builtin(__builtin_amdgcn_sinf)
  return __builtin_amdgcn_sinf(x);
#else
  return __sinf(6.28318530717958647692f*x);
#endif
}
__device__ __forceinline__ float cos2pi(float x){
#if __has_builtin(__builtin_amdgcn_cosf)
  return __builtin_amdgcn_cosf(x);
#else
  return __cosf(6.28318530717958647692f*x);
#endif
}

// unnormalized 8-point DFT. S=-1: forward; S=+1: conjugate (8*inverse)
template<int S>
__device__ __forceinline__ void dft8(float* xr, float* xi){
  const float r2 = 0.70710678118654752f;
  float tr[4], ti[4], mr[4], mi[4];
#pragma unroll
  for(int n=0;n<4;n++){
    tr[n]=xr[n]+xr[n+4]; ti[n]=xi[n]+xi[n+4];
    mr[n]=xr[n]-xr[n+4]; mi[n]=xi[n]-xi[n+4];
  }
  float or_[4], oi_[4];
  or_[0]=mr[0];               oi_[0]=mi[0];
  or_[1]=r2*(mr[1]-S*mi[1]);  oi_[1]=r2*(mi[1]+S*mr[1]);
  or_[2]=-S*mi[2];            oi_[2]= S*mr[2];
  or_[3]=-r2*(mr[3]+S*mi[3]); oi_[3]= r2*(S*mr[3]-mi[3]);
  float s0r=tr[0]+tr[2], s0i=ti[0]+ti[2];
  float s1r=tr[1]+tr[3], s1i=ti[1]+ti[3];
  float d0r=tr[0]-tr[2], d0i=ti[0]-ti[2];
  float d1r=tr[1]-tr[3], d1i=ti[1]-ti[3];
  xr[0]=s0r+s1r;   xi[0]=s0i+s1i;
  xr[4]=s0r-s1r;   xi[4]=s0i-s1i;
  xr[2]=d0r-S*d1i; xi[2]=d0i+S*d1r;
  xr[6]=d0r+S*d1i; xi[6]=d0i-S*d1r;
  float p0r=or_[0]+or_[2], p0i=oi_[0]+oi_[2];
  float p1r=or_[1]+or_[3], p1i=oi_[1]+oi_[3];
  float e0r=or_[0]-or_[2], e0i=oi_[0]-oi_[2];
  float e1r=or_[1]-or_[3], e1i=oi_[1]-oi_[3];
  xr[1]=p0r+p1r;   xi[1]=p0i+p1i;
  xr[5]=p0r-p1r;   xi[5]=p0i-p1i;
  xr[3]=e0r-S*e1i; xi[3]=e0i+S*e1r;
  xr[7]=e0r+S*e1i; xi[7]=e0i-S*e1r;
}

template<int S>
__device__ __forceinline__ void twid(float* xr, float* xi, int n, float invM){
  float f = (float)n * invM;
  float c1 = cos2pi(f), s1 = (float)S * sin2pi(f);
  float cr=c1, ci=s1;
#pragma unroll
  for(int q=1;q<8;q++){
    float a=xr[q], b=xi[q];
    xr[q]=a*cr-b*ci; xi[q]=a*ci+b*cr;
    float nr=cr*c1-ci*s1, ni=cr*s1+ci*c1;
    cr=nr; ci=ni;
  }
}

// ---------- K1: paired-row real FFT -> half spectrum (natural w, 0..256) ----------
__global__ __launch_bounds__(256) void k_row_rfft(const float* __restrict__ x, float2* __restrict__ Fh,
                                                  int c0, unsigned long long fh_cs){
  __shared__ float lre[4][512];
  __shared__ float lim[4][512];
  const int wv = threadIdx.x>>6, t = threadIdx.x&63;
  const int pr = blockIdx.x*4 + wv;             // pair index: b*256 + r2
  const int b = pr>>8, r2 = pr&255;
  const int cc = blockIdx.y, c = c0 + cc;
  const float* sa = x + (size_t)b*(NC*HH*WW) + (size_t)c*HH*WW + (size_t)(2*r2)*WW;
  const float* sb = sa + WW;
  float xr[8], xi[8];
#pragma unroll
  for(int i=0;i<8;i++){ xr[i]=sa[t+64*i]; xi[i]=sb[t+64*i]; }
  dft8<-1>(xr,xi);
  twid<-1>(xr,xi,t,1.0f/512.0f);
#pragma unroll
  for(int q=0;q<8;q++){ int p=swz(t+64*q); lre[wv][p]=xr[q]; lim[wv][p]=xi[q]; }
  __syncthreads();
  const int beta=t>>3, n1=t&7, base1=64*beta+n1;
#pragma unroll
  for(int i=0;i<8;i++){ int p=swz(base1+8*i); xr[i]=lre[wv][p]; xi[i]=lim[wv][p]; }
  dft8<-1>(xr,xi);
  twid<-1>(xr,xi,n1,1.0f/64.0f);
#pragma unroll
  for(int q=0;q<8;q++){ int p=swz(base1+8*q); lre[wv][p]=xr[q]; lim[wv][p]=xi[q]; }
  __syncthreads();
#pragma unroll
  for(int i=0;i<8;i++){ int p=swz(8*t+i); xr[i]=lre[wv][p]; xi[i]=lim[wv][p]; }
  dft8<-1>(xr,xi);
  // scatter to natural order: slot 8t+i holds Z[rev9(8t+i)]
  __syncthreads();
#pragma unroll
  for(int i=0;i<8;i++){ int nat = 64*i + 8*(t&7) + (t>>3); lre[wv][nat]=xr[i]; lim[wv][nat]=xi[i]; }
  __syncthreads();
  // Hermitian unpack: Ra[w]=(Z[w]+conj(Z[-w]))/2, Rb[w]=-i(Z[w]-conj(Z[-w]))/2
  float2* Fa = Fh + (size_t)cc*fh_cs + (size_t)(b*HH + 2*r2)*W2;
  float2* Fb = Fa + W2;
#pragma unroll
  for(int j=0;j<5;j++){
    int w = t + 64*j;
    if(w<=256){
      int m = (512-w)&511;
      float pr_=lre[wv][w], pi_=lim[wv][w], qr=lre[wv][m], qi=lim[wv][m];
      Fa[w]=make_float2(0.5f*(pr_+qr), 0.5f*(pi_-qi));
      Fb[w]=make_float2(0.5f*(pi_+qi), 0.5f*(qr-pr_));
    }
  }
}

// ---------- K2: column FFT over h (natural h in -> digit-rev h out), 512 threads ----------
__global__ __launch_bounds__(512) void k_col_fft(float2* __restrict__ Fh, unsigned long long fh_cs){
  __shared__ float sre[512*17];
  __shared__ float sim[512*17];
  const int b    = blockIdx.x/17;
  const int tile = blockIdx.x - b*17;
  const int w0   = tile*16;
  float2* base = Fh + (size_t)blockIdx.y*fh_cs + (size_t)b*HH*W2 + w0;
  const int c = threadIdx.x&15, w = threadIdx.x>>4;   // w in 0..31
#pragma unroll
  for(int k=0;k<16;k++){
    int f = threadIdx.x + 512*k;
    int r = f>>4, col = f&15;
    float2 v = base[(size_t)r*W2 + col];
    sre[r*17+col]=v.x; sim[r*17+col]=v.y;
  }
  __syncthreads();
#pragma unroll
  for(int jj=0;jj<2;jj++){                      // stage 0
    int n = jj*32 + w;
    float xr[8], xi[8];
#pragma unroll
    for(int i=0;i<8;i++){ int e=n+64*i; xr[i]=sre[e*17+c]; xi[i]=sim[e*17+c]; }
    dft8<-1>(xr,xi);
    twid<-1>(xr,xi,n,1.0f/512.0f);
#pragma unroll
    for(int q=0;q<8;q++){ int e=n+64*q; sre[e*17+c]=xr[q]; sim[e*17+c]=xi[q]; }
  }
  __syncthreads();
#pragma unroll
  for(int jj=0;jj<2;jj++){                      // stage 1
    int m = jj*32 + w;
    int bb = m>>3, nn = m&7, bs = 64*bb+nn;
    float xr[8], xi[8];
#pragma unroll
    for(int i=0;i<8;i++){ int e=bs+8*i; xr[i]=sre[e*17+c]; xi[i]=sim[e*17+c]; }
    dft8<-1>(xr,xi);
    twid<-1>(xr,xi,nn,1.0f/64.0f);
#pragma unroll
    for(int q=0;q<8;q++){ int e=bs+8*q; sre[e*17+c]=xr[q]; sim[e*17+c]=xi[q]; }
  }
  __syncthreads();
#pragma unroll
  for(int jj=0;jj<2;jj++){                      // stage 2 (no twiddle)
    int m = jj*32+w;
    float xr[8], xi[8];
#pragma unroll
    for(int i=0;i<8;i++){ int e=8*m+i; xr[i]=sre[e*17+c]; xi[i]=sim[e*17+c]; }
    dft8<-1>(xr,xi);
#pragma unroll
    for(int q=0;q<8;q++){ int e=8*m+q; sre[e*17+c]=xr[q]; sim[e*17+c]=xi[q]; }
  }
  __syncthreads();
#pragma unroll
  for(int k=0;k<16;k++){
    int f=threadIdx.x+512*k;
    int r=f>>4, col=f&15;
    if(w0+col<=256)
      base[(size_t)r*W2+col]=make_float2(sre[r*17+col], sim[r*17+col]);
  }
}

// ---------- K3: sum(running_amp) ----------
__global__ __launch_bounds__(256) void k_rsum(const float* __restrict__ ra, float* __restrict__ out, int n){
  float s=0.f;
  for(int i=blockIdx.x*256+threadIdx.x; i<n; i+=gridDim.x*256) s+=ra[i];
#pragma unroll
  for(int off=32;off>=1;off>>=1) s += __shfl_down(s, off, 64);
  if((threadIdx.x&63)==0) atomicAdd(out, s);
}

// ---------- K4: batch-mean |F| + symmetrized EMA amplitude A ----------
__global__ __launch_bounds__(256) void k_amp(const float2* __restrict__ Fh, unsigned long long fh_cs,
                                             const float* __restrict__ ra, const float* __restrict__ rsum,
                                             float* __restrict__ A, unsigned long long a_cs, int c0){
  int f = blockIdx.x*256 + threadIdx.x;         // 0 .. 512*272-1
  int p = f/W2, w = f - p*W2;                   // p = digit-rev h slot, w natural
  if(w>256) return;
  const int cc = blockIdx.y, c = c0 + cc;
  const float2* Fc = Fh + (size_t)cc*fh_cs;
  const float* rac = ra + (size_t)c*HH*WW;
  float s=0.f;
#pragma unroll 8
  for(int b=0;b<NB;b++){
    float2 v = Fc[((size_t)b*HH + p)*W2 + w];
    s += sqrtf(v.x*v.x+v.y*v.y);
  }
  float mean = s*(1.0f/32.0f);
  int h = rev9(p);
  int hs =(h+256)&511, ws =(w+256)&511;
  int hs2=(256-h)&511, ws2=(256-w)&511;
  float a_ = (rsum[0]==0.0f) ? mean
           : 0.45f*(rac[hs*WW+ws] + rac[hs2*WW+ws2]) + 0.1f*mean;
  A[(size_t)cc*a_cs + f]=a_;
}

// ---------- K5: magnitude substitution + column IFFT (digit-rev h in -> natural h out), 512 threads ----------
__global__ __launch_bounds__(512) void k_col_ifft(float2* __restrict__ Fh, unsigned long long fh_cs,
                                                  const float* __restrict__ A, unsigned long long a_cs){
  __shared__ float sre[512*17];
  __shared__ float sim[512*17];
  const int b    = blockIdx.x/17;
  const int tile = blockIdx.x - b*17;
  const int w0   = tile*16;
  float2* base = Fh + (size_t)blockIdx.y*fh_cs + (size_t)b*HH*W2 + w0;
  const float* Aa = A + (size_t)blockIdx.y*a_cs + w0;
  const int c = threadIdx.x&15, w = threadIdx.x>>4;
  const float invN2 = 1.0f/262144.0f;
#pragma unroll
  for(int k=0;k<16;k++){
    int f=threadIdx.x+512*k;
    int r=f>>4, col=f&15;
    float2 v = base[(size_t)r*W2+col];
    float amp = Aa[(size_t)r*W2+col];
    float mag = sqrtf(v.x*v.x + v.y*v.y);
    float fr, fi;
    if(mag > 0.f){ float sc = amp*invN2/mag; fr=v.x*sc; fi=v.y*sc; }
    else         { fr = amp*invN2; fi=0.f; }
    sre[r*17+col]=fr; sim[r*17+col]=fi;
  }
  __syncthreads();
#pragma unroll
  for(int jj=0;jj<2;jj++){                      // inverse of stage 2
    int m = jj*32+w;
    float xr[8], xi[8];
#pragma unroll
    for(int q=0;q<8;q++){ int e=8*m+q; xr[q]=sre[e*17+c]; xi[q]=sim[e*17+c]; }
    dft8<1>(xr,xi);
#pragma unroll
    for(int i=0;i<8;i++){ int e=8*m+i; sre[e*17+c]=xr[i]; sim[e*17+c]=xi[i]; }
  }
  __syncthreads();
#pragma unroll
  for(int jj=0;jj<2;jj++){                      // inverse of stage 1
    int m = jj*32 + w;
    int bb = m>>3, nn = m&7, bs = 64*bb+nn;
    float xr[8], xi[8];
#pragma unroll
    for(int q=0;q<8;q++){ int e=bs+8*q; xr[q]=sre[e*17+c]; xi[q]=sim[e*17+c]; }
    twid<1>(xr,xi,nn,1.0f/64.0f);
    dft8<1>(xr,xi);
#pragma unroll
    for(int i=0;i<8;i++){ int e=bs+8*i; sre[e*17+c]=xr[i]; sim[e*17+c]=xi[i]; }
  }
  __syncthreads();
#pragma unroll
  for(int jj=0;jj<2;jj++){                      // inverse of stage 0 -> natural h
    int n = jj*32+w;
    float xr[8], xi[8];
#pragma unroll
    for(int q=0;q<8;q++){ int e=n+64*q; xr[q]=sre[e*17+c]; xi[q]=sim[e*17+c]; }
    twid<1>(xr,xi,n,1.0f/512.0f);
    dft8<1>(xr,xi);
#pragma unroll
    for(int i=0;i<8;i++){ int e=n+64*i; sre[e*17+c]=xr[i]; sim[e*17+c]=xi[i]; }
  }
  __syncthreads();
#pragma unroll
  for(int k=0;k<16;k++){
    int f=threadIdx.x+512*k;
    int r=f>>4, col=f&15;
    if(w0+col<=256)
      base[(size_t)r*W2+col]=make_float2(sre[r*17+col], sim[r*17+col]);
  }
}

// ---------- K6: paired-row inverse real FFT ----------
// Post-column-inverse rows are Hermitian along w: Y[h,512-w]=conj(Y[h,w]).
// Pair adjacent rows (2r,2r+1): Z = rowA + i*rowB, tail from self-conjugate.
__global__ __launch_bounds__(256) void k_row_irfft(const float2* __restrict__ Fh, unsigned long long fh_cs,
                                                   float* __restrict__ out, int c0){
  __shared__ float gAr[4][264], gAi[4][264], gBr[4][264], gBi[4][264];
  __shared__ float lre[4][512], lim[4][512];
  const int wv=threadIdx.x>>6, t=threadIdx.x&63;
  const int pr = blockIdx.x*4+wv;               // b*256 + r2
  const int b = pr>>8, r2 = pr&255;
  const int cc = blockIdx.y, c = c0 + cc;
  const float2* Rp = Fh + (size_t)cc*fh_cs + (size_t)(b*HH + 2*r2)*W2;
  const float2* Rq = Rp + W2;
#pragma unroll
  for(int j=0;j<5;j++){
    int w = t + 64*j;
    if(w<=256){
      float2 v = Rp[w]; gAr[wv][w]=v.x; gAi[wv][w]=v.y;
      float2 u = Rq[w]; gBr[wv][w]=u.x; gBi[wv][w]=u.y;
    }
  }
  __syncthreads();
  // gather digit-reversed slots: slot 8t+i needs Z[rev9(8t+i)]
  float xr[8], xi[8];
#pragma unroll
  for(int i=0;i<8;i++){
    int w = rev9(8*t+i);
    float zr, zi;
    if(w<=256){ zr = gAr[wv][w]-gBi[wv][w]; zi = gAi[wv][w]+gBr[wv][w]; }
    else{
      int m = 512-w;   // row-wise Hermitian: Z[w] = conj(A[m]) + i*conj(B[m])
      zr = gAr[wv][m]+gBi[wv][m]; zi = gBr[wv][m]-gAi[wv][m];
    }
    xr[i]=zr; xi[i]=zi;
  }
  dft8<1>(xr,xi);                               // inverse of stage 2
#pragma unroll
  for(int i=0;i<8;i++){ int pp=swz(8*t+i); lre[wv][pp]=xr[i]; lim[wv][pp]=xi[i]; }
  __syncthreads();
  const int beta=t>>3, n1=t&7, base1=64*beta+n1;
#pragma unroll
  for(int qq=0;qq<8;qq++){ int pp=swz(base1+8*qq); xr[qq]=lre[wv][pp]; xi[qq]=lim[wv][pp]; }
  twid<1>(xr,xi,n1,1.0f/64.0f);
  dft8<1>(xr,xi);                               // inverse of stage 1
#pragma unroll
  for(int i=0;i<8;i++){ int pp=swz(base1+8*i); lre[wv][pp]=xr[i]; lim[wv][pp]=xi[i]; }
  __syncthreads();
#pragma unroll
  for(int qq=0;qq<8;qq++){ int pp=swz(t+64*qq); xr[qq]=lre[wv][pp]; xi[qq]=lim[wv][pp]; }
  twid<1>(xr,xi,t,1.0f/512.0f);
  dft8<1>(xr,xi);                               // inverse of stage 0 -> natural w
  float* oa = out + (size_t)b*(NC*HH*WW) + (size_t)c*HH*WW + (size_t)(2*r2)*WW;
  float* ob = oa + WW;
#pragma unroll
  for(int i=0;i<8;i++){ oa[t+64*i]=xr[i]; ob[t+64*i]=xi[i]; }
}

// ---------- launch ----------
extern "C" void kernel_launch(void* const* d_in, const int* in_sizes, int n_in,
                              void* d_out, int out_size, void* d_ws, size_t ws_size,
                              hipStream_t stream) {
  const float* x  = (const float*)d_in[0];        // [32,3,512,512]
  const float* ra = (const float*)d_in[1];        // [3,512,512]
  float* out = (float*)d_out;

  const unsigned long long fh_cs = (unsigned long long)NB*HH*W2;   // complex elems / channel
  const unsigned long long a_cs  = (unsigned long long)HH*W2;      // floats / channel
  const size_t fb1 = (size_t)fh_cs*sizeof(float2);                 // 35.65 MB
  const size_t ab1 = (size_t)a_cs*sizeof(float);                   // 0.56 MB
  const size_t need3 = 3*fb1 + 3*ab1 + 64;
  const size_t need1 = fb1 + ab1 + 64;

  if (ws_size >= need3) {
    float2* Fh   = (float2*)d_ws;
    float*  A    = (float*)((char*)d_ws + 3*fb1);
    float*  rsum = (float*)((char*)A + 3*ab1);
    hipMemsetAsync(rsum, 0, sizeof(float), stream);
    k_rsum<<<768,256,0,stream>>>(ra, rsum, NC*HH*WW);
    k_row_rfft <<<dim3(NB*256/4,3), 256, 0, stream>>>(x, Fh, 0, fh_cs);
    k_col_fft  <<<dim3(NB*17,3),    512, 0, stream>>>(Fh, fh_cs);
    k_amp      <<<dim3(HH*W2/256,3),256, 0, stream>>>(Fh, fh_cs, ra, rsum, A, a_cs, 0);
    k_col_ifft <<<dim3(NB*17,3),    512, 0, stream>>>(Fh, fh_cs, A, a_cs);
    k_row_irfft<<<dim3(NB*256/4,3), 256, 0, stream>>>(Fh, fh_cs, out, 0);
  } else if (ws_size >= need1) {
    float2* Fh   = (float2*)d_ws;
    float*  A    = (float*)((char*)d_ws + fb1);
    float*  rsum = (float*)((char*)A + ab1);
    hipMemsetAsync(rsum, 0, sizeof(float), stream);
    k_rsum<<<768,256,0,stream>>>(ra, rsum, NC*HH*WW);
    for(int c=0;c<NC;c++){
      k_row_rfft <<<dim3(NB*256/4,1), 256, 0, stream>>>(x, Fh, c, 0ULL);
      k_col_fft  <<<dim3(NB*17,1),    512, 0, stream>>>(Fh, 0ULL);
      k_amp      <<<dim3(HH*W2/256,1),256, 0, stream>>>(Fh, 0ULL, ra, rsum, A, 0ULL, c);
      k_col_ifft <<<dim3(NB*17,1),    512, 0, stream>>>(Fh, 0ULL, A, 0ULL);
      k_row_irfft<<<dim3(NB*256/4,1), 256, 0, stream>>>(Fh, 0ULL, out, c);
    }
  }
}

// Round 5
// 228.896 us; speedup vs baseline: 1.9908x; 1.0556x over previous
//
#include <hip/hip_runtime.h>
#include <math.h>

#define NB 32
#define NC 3
#define HH 512
#define WW 512
#define W2 272   // padded half-spectrum width: cols 0..256 valid, 257..271 pad

// ---------- helpers ----------

// XOR swizzle for per-line LDS FFT: 2-way (free) bank conflicts on all 3 stages
__device__ __forceinline__ int swz(int i){ int h=(i>>6)&7; return i ^ (h<<3) ^ h; }
// base-8 digit reversal of 9-bit index
__device__ __forceinline__ int rev9(int k){ return ((k&7)<<6) | (k&56) | (k>>6); }

__device__ __forceinline__ float sin2pi(float x){
#if __has_builtin(__builtin_amdgcn_sinf)
  return __builtin_amdgcn_sinf(x);
#else
  return __sinf(6.28318530717958647692f*x);
#endif
}
__device__ __forceinline__ float cos2pi(float x){
#if __has_builtin(__builtin_amdgcn_cosf)
  return __builtin_amdgcn_cosf(x);
#else
  return __cosf(6.28318530717958647692f*x);
#endif
}

// unnormalized 8-point DFT. S=-1: forward; S=+1: conjugate (8*inverse)
template<int S>
__device__ __forceinline__ void dft8(float* xr, float* xi){
  const float r2 = 0.70710678118654752f;
  float tr[4], ti[4], mr[4], mi[4];
#pragma unroll
  for(int n=0;n<4;n++){
    tr[n]=xr[n]+xr[n+4]; ti[n]=xi[n]+xi[n+4];
    mr[n]=xr[n]-xr[n+4]; mi[n]=xi[n]-xi[n+4];
  }
  float or_[4], oi_[4];
  or_[0]=mr[0];               oi_[0]=mi[0];
  or_[1]=r2*(mr[1]-S*mi[1]);  oi_[1]=r2*(mi[1]+S*mr[1]);
  or_[2]=-S*mi[2];            oi_[2]= S*mr[2];
  or_[3]=-r2*(mr[3]+S*mi[3]); oi_[3]= r2*(S*mr[3]-mi[3]);
  float s0r=tr[0]+tr[2], s0i=ti[0]+ti[2];
  float s1r=tr[1]+tr[3], s1i=ti[1]+ti[3];
  float d0r=tr[0]-tr[2], d0i=ti[0]-ti[2];
  float d1r=tr[1]-tr[3], d1i=ti[1]-ti[3];
  xr[0]=s0r+s1r;   xi[0]=s0i+s1i;
  xr[4]=s0r-s1r;   xi[4]=s0i-s1i;
  xr[2]=d0r-S*d1i; xi[2]=d0i+S*d1r;
  xr[6]=d0r+S*d1i; xi[6]=d0i-S*d1r;
  float p0r=or_[0]+or_[2], p0i=oi_[0]+oi_[2];
  float p1r=or_[1]+or_[3], p1i=oi_[1]+oi_[3];
  float e0r=or_[0]-or_[2], e0i=oi_[0]-oi_[2];
  float e1r=or_[1]-or_[3], e1i=oi_[1]-oi_[3];
  xr[1]=p0r+p1r;   xi[1]=p0i+p1i;
  xr[5]=p0r-p1r;   xi[5]=p0i-p1i;
  xr[3]=e0r-S*e1i; xi[3]=e0i+S*e1r;
  xr[7]=e0r+S*e1i; xi[7]=e0i-S*e1r;
}

template<int S>
__device__ __forceinline__ void twid(float* xr, float* xi, int n, float invM){
  float f = (float)n * invM;
  float c1 = cos2pi(f), s1 = (float)S * sin2pi(f);
  float cr=c1, ci=s1;
#pragma unroll
  for(int q=1;q<8;q++){
    float a=xr[q], b=xi[q];
    xr[q]=a*cr-b*ci; xi[q]=a*ci+b*cr;
    float nr=cr*c1-ci*s1, ni=cr*s1+ci*c1;
    cr=nr; ci=ni;
  }
}

// ---------- K1: paired-row real FFT -> half spectrum (natural w, 0..256) ----------
__global__ __launch_bounds__(256) void k_row_rfft(const float* __restrict__ x, float2* __restrict__ Fh,
                                                  unsigned long long fh_cs){
  __shared__ float lre[4][512];
  __shared__ float lim[4][512];
  const int wv = threadIdx.x>>6, t = threadIdx.x&63;
  const int pr = blockIdx.x*4 + wv;             // pair index: b*256 + r2
  const int b = pr>>8, r2 = pr&255;
  const int cc = blockIdx.y;
  const float* sa = x + (size_t)b*(NC*HH*WW) + (size_t)cc*HH*WW + (size_t)(2*r2)*WW;
  const float* sb = sa + WW;
  float xr[8], xi[8];
#pragma unroll
  for(int i=0;i<8;i++){ xr[i]=sa[t+64*i]; xi[i]=sb[t+64*i]; }
  dft8<-1>(xr,xi);
  twid<-1>(xr,xi,t,1.0f/512.0f);
#pragma unroll
  for(int q=0;q<8;q++){ int p=swz(t+64*q); lre[wv][p]=xr[q]; lim[wv][p]=xi[q]; }
  __syncthreads();
  const int beta=t>>3, n1=t&7, base1=64*beta+n1;
#pragma unroll
  for(int i=0;i<8;i++){ int p=swz(base1+8*i); xr[i]=lre[wv][p]; xi[i]=lim[wv][p]; }
  dft8<-1>(xr,xi);
  twid<-1>(xr,xi,n1,1.0f/64.0f);
#pragma unroll
  for(int q=0;q<8;q++){ int p=swz(base1+8*q); lre[wv][p]=xr[q]; lim[wv][p]=xi[q]; }
  __syncthreads();
#pragma unroll
  for(int i=0;i<8;i++){ int p=swz(8*t+i); xr[i]=lre[wv][p]; xi[i]=lim[wv][p]; }
  dft8<-1>(xr,xi);
  // scatter to natural order: slot 8t+i holds Z[rev9(8t+i)]
  __syncthreads();
#pragma unroll
  for(int i=0;i<8;i++){ int nat = 64*i + 8*(t&7) + (t>>3); lre[wv][nat]=xr[i]; lim[wv][nat]=xi[i]; }
  __syncthreads();
  // Hermitian unpack: Ra[w]=(Z[w]+conj(Z[-w]))/2, Rb[w]=-i(Z[w]-conj(Z[-w]))/2
  float2* Fa = Fh + (size_t)cc*fh_cs + (size_t)(b*HH + 2*r2)*W2;
  float2* Fb = Fa + W2;
#pragma unroll
  for(int j=0;j<5;j++){
    int w = t + 64*j;
    if(w<=256){
      int m = (512-w)&511;
      float pr_=lre[wv][w], pi_=lim[wv][w], qr=lre[wv][m], qi=lim[wv][m];
      Fa[w]=make_float2(0.5f*(pr_+qr), 0.5f*(pi_-qi));
      Fb[w]=make_float2(0.5f*(pi_+qi), 0.5f*(qr-pr_));
    }
  }
}

// ---------- K2: column FFT (3-phase) + fused |F| batch accumulation ----------
// phase A: stage 0 straight from global; phase B: stage 1 in LDS; phase C: stage 2
// from LDS -> registers -> global store + atomic |F| accumulate.
__global__ __launch_bounds__(512) void k_col_fft(float2* __restrict__ Fh, unsigned long long fh_cs,
                                                 float* __restrict__ Asum, unsigned long long a_cs){
  __shared__ float sre[512*17];
  __shared__ float sim[512*17];
  const int b    = blockIdx.x/17;
  const int tile = blockIdx.x - b*17;
  const int w0   = tile*16;
  const int cc   = blockIdx.y;
  float2* base = Fh + (size_t)cc*fh_cs + (size_t)b*HH*W2 + w0;
  float*  As   = Asum + (size_t)cc*a_cs + w0;
  const int c = threadIdx.x&15, w = threadIdx.x>>4;   // w in 0..31
#pragma unroll
  for(int jj=0;jj<2;jj++){                      // phase A: stage 0 from global
    int n = jj*32 + w;
    float xr[8], xi[8];
#pragma unroll
    for(int i=0;i<8;i++){ float2 v = base[(size_t)(n+64*i)*W2 + c]; xr[i]=v.x; xi[i]=v.y; }
    dft8<-1>(xr,xi);
    twid<-1>(xr,xi,n,1.0f/512.0f);
#pragma unroll
    for(int q=0;q<8;q++){ int e=n+64*q; sre[e*17+c]=xr[q]; sim[e*17+c]=xi[q]; }
  }
  __syncthreads();
#pragma unroll
  for(int jj=0;jj<2;jj++){                      // phase B: stage 1 in LDS
    int m = jj*32 + w;
    int bb = m>>3, nn = m&7, bs = 64*bb+nn;
    float xr[8], xi[8];
#pragma unroll
    for(int i=0;i<8;i++){ int e=bs+8*i; xr[i]=sre[e*17+c]; xi[i]=sim[e*17+c]; }
    dft8<-1>(xr,xi);
    twid<-1>(xr,xi,nn,1.0f/64.0f);
#pragma unroll
    for(int q=0;q<8;q++){ int e=bs+8*q; sre[e*17+c]=xr[q]; sim[e*17+c]=xi[q]; }
  }
  __syncthreads();
#pragma unroll
  for(int jj=0;jj<2;jj++){                      // phase C: stage 2 -> global + amp
    int m = jj*32+w;
    float xr[8], xi[8];
#pragma unroll
    for(int i=0;i<8;i++){ int e=8*m+i; xr[i]=sre[e*17+c]; xi[i]=sim[e*17+c]; }
    dft8<-1>(xr,xi);
    if(w0+c<=256){
#pragma unroll
      for(int q=0;q<8;q++){
        int p=8*m+q;
        base[(size_t)p*W2+c]=make_float2(xr[q],xi[q]);
        atomicAdd(&As[(size_t)p*W2+c], sqrtf(xr[q]*xr[q]+xi[q]*xi[q]));
      }
    }
  }
}

// ---------- K3: sum(running_amp) ----------
__global__ __launch_bounds__(256) void k_rsum(const float* __restrict__ ra, float* __restrict__ out, int n){
  float s=0.f;
  for(int i=blockIdx.x*256+threadIdx.x; i<n; i+=gridDim.x*256) s+=ra[i];
#pragma unroll
  for(int off=32;off>=1;off>>=1) s += __shfl_down(s, off, 64);
  if((threadIdx.x&63)==0) atomicAdd(out, s);
}

// ---------- K4: finalize amplitude A from Asum + running_amp ----------
__global__ __launch_bounds__(256) void k_amp_fin(const float* __restrict__ Asum, unsigned long long a_cs,
                                                 const float* __restrict__ ra, const float* __restrict__ rsum,
                                                 float* __restrict__ A){
  int f = blockIdx.x*256 + threadIdx.x;         // 0 .. 512*272-1
  if(f >= HH*W2) return;
  int p = f/W2, w = f - p*W2;                   // p = digit-rev h slot, w natural
  if(w>256) return;
  const int cc = blockIdx.y;
  float mean = Asum[(size_t)cc*a_cs + f]*(1.0f/32.0f);
  const float* rac = ra + (size_t)cc*HH*WW;
  int h = rev9(p);
  int hs =(h+256)&511, ws =(w+256)&511;
  int hs2=(256-h)&511, ws2=(256-w)&511;
  float a_ = (rsum[0]==0.0f) ? mean
           : 0.45f*(rac[hs*WW+ws] + rac[hs2*WW+ws2]) + 0.1f*mean;
  A[(size_t)cc*a_cs + f]=a_;
}

// ---------- K5: magnitude substitution + column IFFT (3-phase) ----------
__global__ __launch_bounds__(512) void k_col_ifft(float2* __restrict__ Fh, unsigned long long fh_cs,
                                                  const float* __restrict__ A, unsigned long long a_cs){
  __shared__ float sre[512*17];
  __shared__ float sim[512*17];
  const int b    = blockIdx.x/17;
  const int tile = blockIdx.x - b*17;
  const int w0   = tile*16;
  const int cc   = blockIdx.y;
  float2* base = Fh + (size_t)cc*fh_cs + (size_t)b*HH*W2 + w0;
  const float* Aa = A + (size_t)cc*a_cs + w0;
  const int c = threadIdx.x&15, w = threadIdx.x>>4;
  const float invN2 = 1.0f/262144.0f;
#pragma unroll
  for(int jj=0;jj<2;jj++){                      // phase A: scale + inverse stage 2, from global
    int m = jj*32+w;
    float xr[8], xi[8];
#pragma unroll
    for(int q=0;q<8;q++){
      int p=8*m+q;
      float2 v = base[(size_t)p*W2+c];
      float amp = Aa[(size_t)p*W2+c];
      float m2 = v.x*v.x + v.y*v.y;
      float sc = amp*invN2*__frsqrt_rn(m2);
      if(m2 > 0.f){ xr[q]=v.x*sc; xi[q]=v.y*sc; }
      else        { xr[q]=amp*invN2; xi[q]=0.f; }   // angle(0)=0
    }
    dft8<1>(xr,xi);
#pragma unroll
    for(int i=0;i<8;i++){ int e=8*m+i; sre[e*17+c]=xr[i]; sim[e*17+c]=xi[i]; }
  }
  __syncthreads();
#pragma unroll
  for(int jj=0;jj<2;jj++){                      // phase B: inverse stage 1 in LDS
    int m = jj*32 + w;
    int bb = m>>3, nn = m&7, bs = 64*bb+nn;
    float xr[8], xi[8];
#pragma unroll
    for(int q=0;q<8;q++){ int e=bs+8*q; xr[q]=sre[e*17+c]; xi[q]=sim[e*17+c]; }
    twid<1>(xr,xi,nn,1.0f/64.0f);
    dft8<1>(xr,xi);
#pragma unroll
    for(int i=0;i<8;i++){ int e=bs+8*i; sre[e*17+c]=xr[i]; sim[e*17+c]=xi[i]; }
  }
  __syncthreads();
#pragma unroll
  for(int jj=0;jj<2;jj++){                      // phase C: inverse stage 0 -> global (natural h)
    int n = jj*32+w;
    float xr[8], xi[8];
#pragma unroll
    for(int q=0;q<8;q++){ int e=n+64*q; xr[q]=sre[e*17+c]; xi[q]=sim[e*17+c]; }
    twid<1>(xr,xi,n,1.0f/512.0f);
    dft8<1>(xr,xi);
    if(w0+c<=256){
#pragma unroll
      for(int i=0;i<8;i++){ base[(size_t)(n+64*i)*W2+c]=make_float2(xr[i],xi[i]); }
    }
  }
}

// ---------- K6: paired-row inverse real FFT ----------
// Post-column-inverse rows are Hermitian along w: Y[h,512-w]=conj(Y[h,w]).
// Pair adjacent rows (2r,2r+1): Z = rowA + i*rowB, tail from self-conjugate.
__global__ __launch_bounds__(256) void k_row_irfft(const float2* __restrict__ Fh, unsigned long long fh_cs,
                                                   float* __restrict__ out){
  __shared__ float gAr[4][264], gAi[4][264], gBr[4][264], gBi[4][264];
  __shared__ float lre[4][512], lim[4][512];
  const int wv=threadIdx.x>>6, t=threadIdx.x&63;
  const int pr = blockIdx.x*4+wv;               // b*256 + r2
  const int b = pr>>8, r2 = pr&255;
  const int cc = blockIdx.y;
  const float2* Rp = Fh + (size_t)cc*fh_cs + (size_t)(b*HH + 2*r2)*W2;
  const float2* Rq = Rp + W2;
#pragma unroll
  for(int j=0;j<5;j++){
    int w = t + 64*j;
    if(w<=256){
      float2 v = Rp[w]; gAr[wv][w]=v.x; gAi[wv][w]=v.y;
      float2 u = Rq[w]; gBr[wv][w]=u.x; gBi[wv][w]=u.y;
    }
  }
  __syncthreads();
  // gather digit-reversed slots: slot 8t+i needs Z[rev9(8t+i)]
  float xr[8], xi[8];
#pragma unroll
  for(int i=0;i<8;i++){
    int w = rev9(8*t+i);
    float zr, zi;
    if(w<=256){ zr = gAr[wv][w]-gBi[wv][w]; zi = gAi[wv][w]+gBr[wv][w]; }
    else{
      int m = 512-w;   // row-wise Hermitian: Z[w] = conj(A[m]) + i*conj(B[m])
      zr = gAr[wv][m]+gBi[wv][m]; zi = gBr[wv][m]-gAi[wv][m];
    }
    xr[i]=zr; xi[i]=zi;
  }
  dft8<1>(xr,xi);                               // inverse of stage 2
#pragma unroll
  for(int i=0;i<8;i++){ int pp=swz(8*t+i); lre[wv][pp]=xr[i]; lim[wv][pp]=xi[i]; }
  __syncthreads();
  const int beta=t>>3, n1=t&7, base1=64*beta+n1;
#pragma unroll
  for(int qq=0;qq<8;qq++){ int pp=swz(base1+8*qq); xr[qq]=lre[wv][pp]; xi[qq]=lim[wv][pp]; }
  twid<1>(xr,xi,n1,1.0f/64.0f);
  dft8<1>(xr,xi);                               // inverse of stage 1
#pragma unroll
  for(int i=0;i<8;i++){ int pp=swz(base1+8*i); lre[wv][pp]=xr[i]; lim[wv][pp]=xi[i]; }
  __syncthreads();
#pragma unroll
  for(int qq=0;qq<8;qq++){ int pp=swz(t+64*qq); xr[qq]=lre[wv][pp]; xi[qq]=lim[wv][pp]; }
  twid<1>(xr,xi,t,1.0f/512.0f);
  dft8<1>(xr,xi);                               // inverse of stage 0 -> natural w
  float* oa = out + (size_t)b*(NC*HH*WW) + (size_t)cc*HH*WW + (size_t)(2*r2)*WW;
  float* ob = oa + WW;
#pragma unroll
  for(int i=0;i<8;i++){ oa[t+64*i]=xr[i]; ob[t+64*i]=xi[i]; }
}

// ---------- launch ----------
extern "C" void kernel_launch(void* const* d_in, const int* in_sizes, int n_in,
                              void* d_out, int out_size, void* d_ws, size_t ws_size,
                              hipStream_t stream) {
  const float* x  = (const float*)d_in[0];        // [32,3,512,512]
  const float* ra = (const float*)d_in[1];        // [3,512,512]
  float* out = (float*)d_out;

  const unsigned long long fh_cs = (unsigned long long)NB*HH*W2;   // complex elems / channel
  const unsigned long long a_cs  = (unsigned long long)HH*W2;      // floats / channel
  const size_t fb3 = (size_t)fh_cs*sizeof(float2)*3;               // 107 MB
  const size_t ab1 = (size_t)a_cs*sizeof(float);                   // 0.56 MB
  // layout: [Fh (3ch)] [Asum (3ch)] [rsum] [A (3ch)]
  const size_t need = fb3 + 3*ab1 + 64 + 3*ab1;
  if (ws_size < need) return;

  float2* Fh   = (float2*)d_ws;
  float*  Asum = (float*)((char*)d_ws + fb3);
  float*  rsum = (float*)((char*)Asum + 3*ab1);
  float*  A    = (float*)((char*)rsum + 64);

  // zero Asum + rsum in one contiguous async memset
  hipMemsetAsync(Asum, 0, 3*ab1 + sizeof(float), stream);
  k_rsum<<<768,256,0,stream>>>(ra, rsum, NC*HH*WW);

  k_row_rfft <<<dim3(NB*256/4,3), 256, 0, stream>>>(x, Fh, fh_cs);
  k_col_fft  <<<dim3(NB*17,3),    512, 0, stream>>>(Fh, fh_cs, Asum, a_cs);
  k_amp_fin  <<<dim3((HH*W2+255)/256,3), 256, 0, stream>>>(Asum, a_cs, ra, rsum, A);
  k_col_ifft <<<dim3(NB*17,3),    512, 0, stream>>>(Fh, fh_cs, A, a_cs);
  k_row_irfft<<<dim3(NB*256/4,3), 256, 0, stream>>>(Fh, fh_cs, out);
}

// Round 6
// 198.834 us; speedup vs baseline: 2.2918x; 1.1512x over previous
//
#include <hip/hip_runtime.h>
#include <hip/hip_fp16.h>
#include <math.h>

#define NB 32
#define NC 3
#define HH 512
#define WW 512
#define W2 272   // padded half-spectrum width: cols 0..256 valid, 257..271 pad

typedef __half2 h2;
typedef unsigned long long ull;

// ---------- helpers ----------

// XOR swizzle for per-line LDS FFT: 2-way (free) bank conflicts on all 3 stages
__device__ __forceinline__ int swz(int i){ int h=(i>>6)&7; return i ^ (h<<3) ^ h; }
// base-8 digit reversal of 9-bit index
__device__ __forceinline__ int rev9(int k){ return ((k&7)<<6) | (k&56) | (k>>6); }

__device__ __forceinline__ float sin2pi(float x){
#if __has_builtin(__builtin_amdgcn_sinf)
  return __builtin_amdgcn_sinf(x);
#else
  return __sinf(6.28318530717958647692f*x);
#endif
}
__device__ __forceinline__ float cos2pi(float x){
#if __has_builtin(__builtin_amdgcn_cosf)
  return __builtin_amdgcn_cosf(x);
#else
  return __cosf(6.28318530717958647692f*x);
#endif
}

// unnormalized 8-point DFT. S=-1: forward; S=+1: conjugate (8*inverse)
template<int S>
__device__ __forceinline__ void dft8(float* xr, float* xi){
  const float r2 = 0.70710678118654752f;
  float tr[4], ti[4], mr[4], mi[4];
#pragma unroll
  for(int n=0;n<4;n++){
    tr[n]=xr[n]+xr[n+4]; ti[n]=xi[n]+xi[n+4];
    mr[n]=xr[n]-xr[n+4]; mi[n]=xi[n]-xi[n+4];
  }
  float or_[4], oi_[4];
  or_[0]=mr[0];               oi_[0]=mi[0];
  or_[1]=r2*(mr[1]-S*mi[1]);  oi_[1]=r2*(mi[1]+S*mr[1]);
  or_[2]=-S*mi[2];            oi_[2]= S*mr[2];
  or_[3]=-r2*(mr[3]+S*mi[3]); oi_[3]= r2*(S*mr[3]-mi[3]);
  float s0r=tr[0]+tr[2], s0i=ti[0]+ti[2];
  float s1r=tr[1]+tr[3], s1i=ti[1]+ti[3];
  float d0r=tr[0]-tr[2], d0i=ti[0]-ti[2];
  float d1r=tr[1]-tr[3], d1i=ti[1]-ti[3];
  xr[0]=s0r+s1r;   xi[0]=s0i+s1i;
  xr[4]=s0r-s1r;   xi[4]=s0i-s1i;
  xr[2]=d0r-S*d1i; xi[2]=d0i+S*d1r;
  xr[6]=d0r+S*d1i; xi[6]=d0i-S*d1r;
  float p0r=or_[0]+or_[2], p0i=oi_[0]+oi_[2];
  float p1r=or_[1]+or_[3], p1i=oi_[1]+oi_[3];
  float e0r=or_[0]-or_[2], e0i=oi_[0]-oi_[2];
  float e1r=or_[1]-or_[3], e1i=oi_[1]-oi_[3];
  xr[1]=p0r+p1r;   xi[1]=p0i+p1i;
  xr[5]=p0r-p1r;   xi[5]=p0i-p1i;
  xr[3]=e0r-S*e1i; xi[3]=e0i+S*e1r;
  xr[7]=e0r+S*e1i; xi[7]=e0i-S*e1r;
}

template<int S>
__device__ __forceinline__ void twid(float* xr, float* xi, int n, float invM){
  float f = (float)n * invM;
  float c1 = cos2pi(f), s1 = (float)S * sin2pi(f);
  float cr=c1, ci=s1;
#pragma unroll
  for(int q=1;q<8;q++){
    float a=xr[q], b=xi[q];
    xr[q]=a*cr-b*ci; xi[q]=a*ci+b*cr;
    float nr=cr*c1-ci*s1, ni=cr*s1+ci*c1;
    cr=nr; ci=ni;
  }
}

// ---------- K1: paired-row real FFT -> half spectrum (half2, natural w 0..256) ----------
// 128 threads = 2 independent waves, per-wave LDS regions
__global__ __launch_bounds__(128) void k_row_rfft(const float* __restrict__ x, h2* __restrict__ Fh,
                                                  ull fh_cs){
  __shared__ float lre[2][512];
  __shared__ float lim[2][512];
  const int wv = threadIdx.x>>6, t = threadIdx.x&63;
  const int pr = blockIdx.x*2 + wv;             // pair index: b*256 + r2
  const int b = pr>>8, r2 = pr&255;
  const int cc = blockIdx.y;
  const float* sa = x + (size_t)b*(NC*HH*WW) + (size_t)cc*HH*WW + (size_t)(2*r2)*WW;
  const float* sb = sa + WW;
  float xr[8], xi[8];
#pragma unroll
  for(int i=0;i<8;i++){ xr[i]=sa[t+64*i]; xi[i]=sb[t+64*i]; }
  dft8<-1>(xr,xi);
  twid<-1>(xr,xi,t,1.0f/512.0f);
#pragma unroll
  for(int q=0;q<8;q++){ int p=swz(t+64*q); lre[wv][p]=xr[q]; lim[wv][p]=xi[q]; }
  __syncthreads();
  const int beta=t>>3, n1=t&7, base1=64*beta+n1;
#pragma unroll
  for(int i=0;i<8;i++){ int p=swz(base1+8*i); xr[i]=lre[wv][p]; xi[i]=lim[wv][p]; }
  dft8<-1>(xr,xi);
  twid<-1>(xr,xi,n1,1.0f/64.0f);
#pragma unroll
  for(int q=0;q<8;q++){ int p=swz(base1+8*q); lre[wv][p]=xr[q]; lim[wv][p]=xi[q]; }
  __syncthreads();
#pragma unroll
  for(int i=0;i<8;i++){ int p=swz(8*t+i); xr[i]=lre[wv][p]; xi[i]=lim[wv][p]; }
  dft8<-1>(xr,xi);
  __syncthreads();
  // scatter to natural order: slot 8t+i holds Z[rev9(8t+i)]
#pragma unroll
  for(int i=0;i<8;i++){ int nat = 64*i + 8*(t&7) + (t>>3); lre[wv][nat]=xr[i]; lim[wv][nat]=xi[i]; }
  __syncthreads();
  // Hermitian unpack: Ra[w]=(Z[w]+conj(Z[-w]))/2, Rb[w]=-i(Z[w]-conj(Z[-w]))/2
  h2* Fa = Fh + (size_t)cc*fh_cs + (size_t)(b*HH + 2*r2)*W2;
  h2* Fb = Fa + W2;
#pragma unroll
  for(int j=0;j<5;j++){
    int w = t + 64*j;
    if(w<=256){
      int m = (512-w)&511;
      float pr_=lre[wv][w], pi_=lim[wv][w], qr=lre[wv][m], qi=lim[wv][m];
      Fa[w]=__float22half2_rn(make_float2(0.5f*(pr_+qr), 0.5f*(pi_-qi)));
      Fb[w]=__float22half2_rn(make_float2(0.5f*(pi_+qi), 0.5f*(qr-pr_)));
    }
  }
}

// ---------- K2: column FFT (3-phase) + fused |F| batch accumulation ----------
__global__ __launch_bounds__(512) void k_col_fft(h2* __restrict__ Fh, ull fh_cs,
                                                 float* __restrict__ Asum, ull a_cs){
  __shared__ float sre[512*17];
  __shared__ float sim[512*17];
  const int b    = blockIdx.x/17;
  const int tile = blockIdx.x - b*17;
  const int w0   = tile*16;
  const int cc   = blockIdx.y;
  h2*    base = Fh + (size_t)cc*fh_cs + (size_t)b*HH*W2 + w0;
  float* As   = Asum + (size_t)cc*a_cs + w0;
  const int c = threadIdx.x&15, w = threadIdx.x>>4;   // w in 0..31
#pragma unroll
  for(int jj=0;jj<2;jj++){                      // phase A: stage 0 from global
    int n = jj*32 + w;
    float xr[8], xi[8];
#pragma unroll
    for(int i=0;i<8;i++){ float2 v = __half22float2(base[(size_t)(n+64*i)*W2 + c]); xr[i]=v.x; xi[i]=v.y; }
    dft8<-1>(xr,xi);
    twid<-1>(xr,xi,n,1.0f/512.0f);
#pragma unroll
    for(int q=0;q<8;q++){ int e=n+64*q; sre[e*17+c]=xr[q]; sim[e*17+c]=xi[q]; }
  }
  __syncthreads();
#pragma unroll
  for(int jj=0;jj<2;jj++){                      // phase B: stage 1 in LDS
    int m = jj*32 + w;
    int bb = m>>3, nn = m&7, bs = 64*bb+nn;
    float xr[8], xi[8];
#pragma unroll
    for(int i=0;i<8;i++){ int e=bs+8*i; xr[i]=sre[e*17+c]; xi[i]=sim[e*17+c]; }
    dft8<-1>(xr,xi);
    twid<-1>(xr,xi,nn,1.0f/64.0f);
#pragma unroll
    for(int q=0;q<8;q++){ int e=bs+8*q; sre[e*17+c]=xr[q]; sim[e*17+c]=xi[q]; }
  }
  __syncthreads();
#pragma unroll
  for(int jj=0;jj<2;jj++){                      // phase C: stage 2 -> global + amp
    int m = jj*32+w;
    float xr[8], xi[8];
#pragma unroll
    for(int i=0;i<8;i++){ int e=8*m+i; xr[i]=sre[e*17+c]; xi[i]=sim[e*17+c]; }
    dft8<-1>(xr,xi);
    if(w0+c<=256){
#pragma unroll
      for(int q=0;q<8;q++){
        int p=8*m+q;
        base[(size_t)p*W2+c]=__float22half2_rn(make_float2(xr[q],xi[q]));
        atomicAdd(&As[(size_t)p*W2+c], sqrtf(xr[q]*xr[q]+xi[q]*xi[q]));
      }
    }
  }
}

// ---------- K3: sum(running_amp) ----------
__global__ __launch_bounds__(256) void k_rsum(const float* __restrict__ ra, float* __restrict__ out, int n){
  float s=0.f;
  for(int i=blockIdx.x*256+threadIdx.x; i<n; i+=gridDim.x*256) s+=ra[i];
#pragma unroll
  for(int off=32;off>=1;off>>=1) s += __shfl_down(s, off, 64);
  if((threadIdx.x&63)==0) atomicAdd(out, s);
}

// ---------- K4: finalize amplitude A from Asum + running_amp ----------
__global__ __launch_bounds__(256) void k_amp_fin(const float* __restrict__ Asum, ull a_cs,
                                                 const float* __restrict__ ra, const float* __restrict__ rsum,
                                                 float* __restrict__ A){
  int f = blockIdx.x*256 + threadIdx.x;         // 0 .. 512*272-1
  if(f >= HH*W2) return;
  int p = f/W2, w = f - p*W2;                   // p = digit-rev h slot, w natural
  if(w>256) return;
  const int cc = blockIdx.y;
  float mean = Asum[(size_t)cc*a_cs + f]*(1.0f/32.0f);
  const float* rac = ra + (size_t)cc*HH*WW;
  int h = rev9(p);
  int hs =(h+256)&511, ws =(w+256)&511;
  int hs2=(256-h)&511, ws2=(256-w)&511;
  float a_ = (rsum[0]==0.0f) ? mean
           : 0.45f*(rac[hs*WW+ws] + rac[hs2*WW+ws2]) + 0.1f*mean;
  A[(size_t)cc*a_cs + f]=a_;
}

// ---------- K5: magnitude substitution + column IFFT (3-phase) ----------
__global__ __launch_bounds__(512) void k_col_ifft(h2* __restrict__ Fh, ull fh_cs,
                                                  const float* __restrict__ A, ull a_cs){
  __shared__ float sre[512*17];
  __shared__ float sim[512*17];
  const int b    = blockIdx.x/17;
  const int tile = blockIdx.x - b*17;
  const int w0   = tile*16;
  const int cc   = blockIdx.y;
  h2* base = Fh + (size_t)cc*fh_cs + (size_t)b*HH*W2 + w0;
  const float* Aa = A + (size_t)cc*a_cs + w0;
  const int c = threadIdx.x&15, w = threadIdx.x>>4;
  const float invN2 = 1.0f/262144.0f;
#pragma unroll
  for(int jj=0;jj<2;jj++){                      // phase A: scale + inverse stage 2, from global
    int m = jj*32+w;
    float xr[8], xi[8];
#pragma unroll
    for(int q=0;q<8;q++){
      int p=8*m+q;
      float2 v = __half22float2(base[(size_t)p*W2+c]);
      float amp = Aa[(size_t)p*W2+c];
      float m2 = v.x*v.x + v.y*v.y;
      float sc = amp*invN2*__frsqrt_rn(m2);
      if(m2 > 0.f){ xr[q]=v.x*sc; xi[q]=v.y*sc; }
      else        { xr[q]=amp*invN2; xi[q]=0.f; }   // angle(0)=0
    }
    dft8<1>(xr,xi);
#pragma unroll
    for(int i=0;i<8;i++){ int e=8*m+i; sre[e*17+c]=xr[i]; sim[e*17+c]=xi[i]; }
  }
  __syncthreads();
#pragma unroll
  for(int jj=0;jj<2;jj++){                      // phase B: inverse stage 1 in LDS
    int m = jj*32 + w;
    int bb = m>>3, nn = m&7, bs = 64*bb+nn;
    float xr[8], xi[8];
#pragma unroll
    for(int q=0;q<8;q++){ int e=bs+8*q; xr[q]=sre[e*17+c]; xi[q]=sim[e*17+c]; }
    twid<1>(xr,xi,nn,1.0f/64.0f);
    dft8<1>(xr,xi);
#pragma unroll
    for(int i=0;i<8;i++){ int e=bs+8*i; sre[e*17+c]=xr[i]; sim[e*17+c]=xi[i]; }
  }
  __syncthreads();
#pragma unroll
  for(int jj=0;jj<2;jj++){                      // phase C: inverse stage 0 -> global (natural h)
    int n = jj*32+w;
    float xr[8], xi[8];
#pragma unroll
    for(int q=0;q<8;q++){ int e=n+64*q; xr[q]=sre[e*17+c]; xi[q]=sim[e*17+c]; }
    twid<1>(xr,xi,n,1.0f/512.0f);
    dft8<1>(xr,xi);
    if(w0+c<=256){
#pragma unroll
      for(int i=0;i<8;i++){ base[(size_t)(n+64*i)*W2+c]=__float22half2_rn(make_float2(xr[i],xi[i])); }
    }
  }
}

// ---------- K6: paired-row inverse real FFT (128 threads = 2 waves) ----------
// Post-column-inverse rows are Hermitian along w: Y[h,512-w]=conj(Y[h,w]).
__global__ __launch_bounds__(128) void k_row_irfft(const h2* __restrict__ Fh, ull fh_cs,
                                                   float* __restrict__ out){
  __shared__ h2 gA[2][264], gB[2][264];
  __shared__ float lre[2][512], lim[2][512];
  const int wv=threadIdx.x>>6, t=threadIdx.x&63;
  const int pr = blockIdx.x*2+wv;               // b*256 + r2
  const int b = pr>>8, r2 = pr&255;
  const int cc = blockIdx.y;
  const h2* Rp = Fh + (size_t)cc*fh_cs + (size_t)(b*HH + 2*r2)*W2;
  const h2* Rq = Rp + W2;
#pragma unroll
  for(int j=0;j<5;j++){
    int w = t + 64*j;
    if(w<=256){ gA[wv][w]=Rp[w]; gB[wv][w]=Rq[w]; }
  }
  __syncthreads();
  // gather digit-reversed slots: slot 8t+i needs Z[rev9(8t+i)]
  float xr[8], xi[8];
#pragma unroll
  for(int i=0;i<8;i++){
    int w = rev9(8*t+i);
    float zr, zi;
    if(w<=256){
      float2 a = __half22float2(gA[wv][w]);
      float2 bb = __half22float2(gB[wv][w]);
      zr = a.x - bb.y; zi = a.y + bb.x;
    }else{
      int m = 512-w;   // row-wise Hermitian: Z[w] = conj(A[m]) + i*conj(B[m])
      float2 a = __half22float2(gA[wv][m]);
      float2 bb = __half22float2(gB[wv][m]);
      zr = a.x + bb.y; zi = bb.x - a.y;
    }
    xr[i]=zr; xi[i]=zi;
  }
  dft8<1>(xr,xi);                               // inverse of stage 2
#pragma unroll
  for(int i=0;i<8;i++){ int pp=swz(8*t+i); lre[wv][pp]=xr[i]; lim[wv][pp]=xi[i]; }
  __syncthreads();
  const int beta=t>>3, n1=t&7, base1=64*beta+n1;
#pragma unroll
  for(int qq=0;qq<8;qq++){ int pp=swz(base1+8*qq); xr[qq]=lre[wv][pp]; xi[qq]=lim[wv][pp]; }
  twid<1>(xr,xi,n1,1.0f/64.0f);
  dft8<1>(xr,xi);                               // inverse of stage 1
#pragma unroll
  for(int i=0;i<8;i++){ int pp=swz(base1+8*i); lre[wv][pp]=xr[i]; lim[wv][pp]=xi[i]; }
  __syncthreads();
#pragma unroll
  for(int qq=0;qq<8;qq++){ int pp=swz(t+64*qq); xr[qq]=lre[wv][pp]; xi[qq]=lim[wv][pp]; }
  twid<1>(xr,xi,t,1.0f/512.0f);
  dft8<1>(xr,xi);                               // inverse of stage 0 -> natural w
  float* oa = out + (size_t)b*(NC*HH*WW) + (size_t)cc*HH*WW + (size_t)(2*r2)*WW;
  float* ob = oa + WW;
#pragma unroll
  for(int i=0;i<8;i++){ oa[t+64*i]=xr[i]; ob[t+64*i]=xi[i]; }
}

// ---------- launch ----------
extern "C" void kernel_launch(void* const* d_in, const int* in_sizes, int n_in,
                              void* d_out, int out_size, void* d_ws, size_t ws_size,
                              hipStream_t stream) {
  const float* x  = (const float*)d_in[0];        // [32,3,512,512]
  const float* ra = (const float*)d_in[1];        // [3,512,512]
  float* out = (float*)d_out;

  const ull fh_cs = (ull)NB*HH*W2;                 // half2 elems / channel
  const ull a_cs  = (ull)HH*W2;                    // floats / channel
  const size_t fb3 = (size_t)fh_cs*sizeof(h2)*3;   // 53.5 MB
  const size_t ab1 = (size_t)a_cs*sizeof(float);   // 0.56 MB
  // layout: [Fh (3ch, half2)] [Asum (3ch)] [rsum] [A (3ch)]
  const size_t need = fb3 + 3*ab1 + 64 + 3*ab1;
  if (ws_size < need) return;

  h2*    Fh   = (h2*)d_ws;
  float* Asum = (float*)((char*)d_ws + fb3);
  float* rsum = (float*)((char*)Asum + 3*ab1);
  float* A    = (float*)((char*)rsum + 64);

  // zero Asum + rsum in one contiguous async memset
  hipMemsetAsync(Asum, 0, 3*ab1 + sizeof(float), stream);
  k_rsum<<<768,256,0,stream>>>(ra, rsum, NC*HH*WW);

  k_row_rfft <<<dim3(NB*256/2,3), 128, 0, stream>>>(x, Fh, fh_cs);
  k_col_fft  <<<dim3(NB*17,3),    512, 0, stream>>>(Fh, fh_cs, Asum, a_cs);
  k_amp_fin  <<<dim3((HH*W2+255)/256,3), 256, 0, stream>>>(Asum, a_cs, ra, rsum, A);
  k_col_ifft <<<dim3(NB*17,3),    512, 0, stream>>>(Fh, fh_cs, A, a_cs);
  k_row_irfft<<<dim3(NB*256/2,3), 128, 0, stream>>>(Fh, fh_cs, out);
}

// Round 7
// 194.353 us; speedup vs baseline: 2.3446x; 1.0231x over previous
//
#include <hip/hip_runtime.h>
#include <hip/hip_fp16.h>
#include <math.h>

#define NB 32
#define NC 3
#define HH 512
#define WW 512
#define W2 272   // padded half-spectrum width: cols 0..256 valid, 257..271 pad

typedef __half2 h2;
typedef unsigned long long ull;

// ---------- helpers ----------

// XOR swizzle for per-line LDS FFT: 2-way (free) bank conflicts on all 3 stages
__device__ __forceinline__ int swz(int i){ int h=(i>>6)&7; return i ^ (h<<3) ^ h; }
// base-8 digit reversal of 9-bit index
__device__ __forceinline__ int rev9(int k){ return ((k&7)<<6) | (k&56) | (k>>6); }

__device__ __forceinline__ float sin2pi(float x){
#if __has_builtin(__builtin_amdgcn_sinf)
  return __builtin_amdgcn_sinf(x);
#else
  return __sinf(6.28318530717958647692f*x);
#endif
}
__device__ __forceinline__ float cos2pi(float x){
#if __has_builtin(__builtin_amdgcn_cosf)
  return __builtin_amdgcn_cosf(x);
#else
  return __cosf(6.28318530717958647692f*x);
#endif
}

// unnormalized 8-point DFT. S=-1: forward; S=+1: conjugate (8*inverse)
template<int S>
__device__ __forceinline__ void dft8(float* xr, float* xi){
  const float r2 = 0.70710678118654752f;
  float tr[4], ti[4], mr[4], mi[4];
#pragma unroll
  for(int n=0;n<4;n++){
    tr[n]=xr[n]+xr[n+4]; ti[n]=xi[n]+xi[n+4];
    mr[n]=xr[n]-xr[n+4]; mi[n]=xi[n]-xi[n+4];
  }
  float or_[4], oi_[4];
  or_[0]=mr[0];               oi_[0]=mi[0];
  or_[1]=r2*(mr[1]-S*mi[1]);  oi_[1]=r2*(mi[1]+S*mr[1]);
  or_[2]=-S*mi[2];            oi_[2]= S*mr[2];
  or_[3]=-r2*(mr[3]+S*mi[3]); oi_[3]= r2*(S*mr[3]-mi[3]);
  float s0r=tr[0]+tr[2], s0i=ti[0]+ti[2];
  float s1r=tr[1]+tr[3], s1i=ti[1]+ti[3];
  float d0r=tr[0]-tr[2], d0i=ti[0]-ti[2];
  float d1r=tr[1]-tr[3], d1i=ti[1]-ti[3];
  xr[0]=s0r+s1r;   xi[0]=s0i+s1i;
  xr[4]=s0r-s1r;   xi[4]=s0i-s1i;
  xr[2]=d0r-S*d1i; xi[2]=d0i+S*d1r;
  xr[6]=d0r+S*d1i; xi[6]=d0i-S*d1r;
  float p0r=or_[0]+or_[2], p0i=oi_[0]+oi_[2];
  float p1r=or_[1]+or_[3], p1i=oi_[1]+oi_[3];
  float e0r=or_[0]-or_[2], e0i=oi_[0]-oi_[2];
  float e1r=or_[1]-or_[3], e1i=oi_[1]-oi_[3];
  xr[1]=p0r+p1r;   xi[1]=p0i+p1i;
  xr[5]=p0r-p1r;   xi[5]=p0i-p1i;
  xr[3]=e0r-S*e1i; xi[3]=e0i+S*e1r;
  xr[7]=e0r+S*e1i; xi[7]=e0i-S*e1r;
}

template<int S>
__device__ __forceinline__ void twid(float* xr, float* xi, int n, float invM){
  float f = (float)n * invM;
  float c1 = cos2pi(f), s1 = (float)S * sin2pi(f);
  float cr=c1, ci=s1;
#pragma unroll
  for(int q=1;q<8;q++){
    float a=xr[q], b=xi[q];
    xr[q]=a*cr-b*ci; xi[q]=a*ci+b*cr;
    float nr=cr*c1-ci*s1, ni=cr*s1+ci*c1;
    cr=nr; ci=ni;
  }
}

// ---------- K1: paired-row real FFT -> half spectrum (half2, natural w 0..256) ----------
// 128 threads = 2 independent waves, per-wave LDS regions
__global__ __launch_bounds__(128) void k_row_rfft(const float* __restrict__ x, h2* __restrict__ Fh,
                                                  ull fh_cs){
  __shared__ float lre[2][512];
  __shared__ float lim[2][512];
  const int wv = threadIdx.x>>6, t = threadIdx.x&63;
  const int pr = blockIdx.x*2 + wv;             // pair index: b*256 + r2
  const int b = pr>>8, r2 = pr&255;
  const int cc = blockIdx.y;
  const float* sa = x + (size_t)b*(NC*HH*WW) + (size_t)cc*HH*WW + (size_t)(2*r2)*WW;
  const float* sb = sa + WW;
  float xr[8], xi[8];
#pragma unroll
  for(int i=0;i<8;i++){ xr[i]=sa[t+64*i]; xi[i]=sb[t+64*i]; }
  dft8<-1>(xr,xi);
  twid<-1>(xr,xi,t,1.0f/512.0f);
#pragma unroll
  for(int q=0;q<8;q++){ int p=swz(t+64*q); lre[wv][p]=xr[q]; lim[wv][p]=xi[q]; }
  __syncthreads();
  const int beta=t>>3, n1=t&7, base1=64*beta+n1;
#pragma unroll
  for(int i=0;i<8;i++){ int p=swz(base1+8*i); xr[i]=lre[wv][p]; xi[i]=lim[wv][p]; }
  dft8<-1>(xr,xi);
  twid<-1>(xr,xi,n1,1.0f/64.0f);
#pragma unroll
  for(int q=0;q<8;q++){ int p=swz(base1+8*q); lre[wv][p]=xr[q]; lim[wv][p]=xi[q]; }
  __syncthreads();
#pragma unroll
  for(int i=0;i<8;i++){ int p=swz(8*t+i); xr[i]=lre[wv][p]; xi[i]=lim[wv][p]; }
  dft8<-1>(xr,xi);
  __syncthreads();
  // scatter to natural order: slot 8t+i holds Z[rev9(8t+i)]
#pragma unroll
  for(int i=0;i<8;i++){ int nat = 64*i + 8*(t&7) + (t>>3); lre[wv][nat]=xr[i]; lim[wv][nat]=xi[i]; }
  __syncthreads();
  // Hermitian unpack: Ra[w]=(Z[w]+conj(Z[-w]))/2, Rb[w]=-i(Z[w]-conj(Z[-w]))/2
  h2* Fa = Fh + (size_t)cc*fh_cs + (size_t)(b*HH + 2*r2)*W2;
  h2* Fb = Fa + W2;
#pragma unroll
  for(int j=0;j<5;j++){
    int w = t + 64*j;
    if(w<=256){
      int m = (512-w)&511;
      float pr_=lre[wv][w], pi_=lim[wv][w], qr=lre[wv][m], qi=lim[wv][m];
      Fa[w]=__float22half2_rn(make_float2(0.5f*(pr_+qr), 0.5f*(pi_-qi)));
      Fb[w]=__float22half2_rn(make_float2(0.5f*(pi_+qi), 0.5f*(qr-pr_)));
    }
  }
}

// ---------- K2: column FFT (3-phase, h2-packed LDS, 4 blocks/CU) ----------
__global__ __launch_bounds__(512, 8) void k_col_fft(h2* __restrict__ Fh, ull fh_cs){
  __shared__ h2 sld[512*17];                    // 34.8 KB -> 4 blocks/CU
  const int b    = blockIdx.x/17;
  const int tile = blockIdx.x - b*17;
  const int w0   = tile*16;
  const int cc   = blockIdx.y;
  h2* base = Fh + (size_t)cc*fh_cs + (size_t)b*HH*W2 + w0;
  const int c = threadIdx.x&15, w = threadIdx.x>>4;   // w in 0..31
#pragma unroll
  for(int jj=0;jj<2;jj++){                      // phase A: stage 0 from global
    int n = jj*32 + w;
    float xr[8], xi[8];
#pragma unroll
    for(int i=0;i<8;i++){ float2 v = __half22float2(base[(size_t)(n+64*i)*W2 + c]); xr[i]=v.x; xi[i]=v.y; }
    dft8<-1>(xr,xi);
    twid<-1>(xr,xi,n,1.0f/512.0f);
#pragma unroll
    for(int q=0;q<8;q++){ int e=n+64*q; sld[e*17+c]=__float22half2_rn(make_float2(xr[q],xi[q])); }
  }
  __syncthreads();
#pragma unroll
  for(int jj=0;jj<2;jj++){                      // phase B: stage 1 in LDS
    int m = jj*32 + w;
    int bb = m>>3, nn = m&7, bs = 64*bb+nn;
    float xr[8], xi[8];
#pragma unroll
    for(int i=0;i<8;i++){ int e=bs+8*i; float2 v=__half22float2(sld[e*17+c]); xr[i]=v.x; xi[i]=v.y; }
    dft8<-1>(xr,xi);
    twid<-1>(xr,xi,nn,1.0f/64.0f);
#pragma unroll
    for(int q=0;q<8;q++){ int e=bs+8*q; sld[e*17+c]=__float22half2_rn(make_float2(xr[q],xi[q])); }
  }
  __syncthreads();
#pragma unroll
  for(int jj=0;jj<2;jj++){                      // phase C: stage 2 -> global
    int m = jj*32+w;
    float xr[8], xi[8];
#pragma unroll
    for(int i=0;i<8;i++){ int e=8*m+i; float2 v=__half22float2(sld[e*17+c]); xr[i]=v.x; xi[i]=v.y; }
    dft8<-1>(xr,xi);
    if(w0+c<=256){
#pragma unroll
      for(int q=0;q<8;q++){
        int p=8*m+q;
        base[(size_t)p*W2+c]=__float22half2_rn(make_float2(xr[q],xi[q]));
      }
    }
  }
}

// ---------- K3: sum(running_amp) ----------
__global__ __launch_bounds__(256) void k_rsum(const float* __restrict__ ra, float* __restrict__ out, int n){
  float s=0.f;
  for(int i=blockIdx.x*256+threadIdx.x; i<n; i+=gridDim.x*256) s+=ra[i];
#pragma unroll
  for(int off=32;off>=1;off>>=1) s += __shfl_down(s, off, 64);
  if((threadIdx.x&63)==0) atomicAdd(out, s);
}

// ---------- K4: batch-mean |F| + symmetrized EMA amplitude A (float2-vectorized) ----------
__global__ __launch_bounds__(256) void k_amp(const h2* __restrict__ Fh, ull fh_cs,
                                             const float* __restrict__ ra, const float* __restrict__ rsum,
                                             float* __restrict__ A, ull a_cs){
  int f2 = blockIdx.x*256 + threadIdx.x;        // 0 .. 512*136-1 (pairs of cols)
  int p = f2/136, w2 = f2 - p*136;              // p = digit-rev h slot
  int w = 2*w2;                                 // natural col (even)
  const int cc = blockIdx.y;
  const float2* Fc = (const float2*)(Fh + (size_t)cc*fh_cs);
  float s0=0.f, s1=0.f;
#pragma unroll 8
  for(int b=0;b<NB;b++){
    float2 two = Fc[(size_t)b*(HH*W2/2) + f2];
    h2 va = ((const h2*)&two)[0], vb = ((const h2*)&two)[1];
    float2 a = __half22float2(va), bq = __half22float2(vb);
    s0 += sqrtf(a.x*a.x + a.y*a.y);
    s1 += sqrtf(bq.x*bq.x + bq.y*bq.y);
  }
  float mean0 = s0*(1.0f/32.0f), mean1 = s1*(1.0f/32.0f);
  const float* rac = ra + (size_t)cc*HH*WW;
  int h = rev9(p);
  int hs =(h+256)&511, hs2=(256-h)&511;
  int ws0 =(w+256)&511, ws20=(256-w)&511;
  int ws1 =(w+257)&511, ws21=(255-w)&511;
  float a0, a1;
  if(rsum[0]==0.0f){ a0=mean0; a1=mean1; }
  else{
    a0 = 0.45f*(rac[hs*WW+ws0] + rac[hs2*WW+ws20]) + 0.1f*mean0;
    a1 = 0.45f*(rac[hs*WW+ws1] + rac[hs2*WW+ws21]) + 0.1f*mean1;
  }
  *(float2*)(A + (size_t)cc*a_cs + (size_t)p*W2 + w) = make_float2(a0, a1);
}

// ---------- K5: magnitude substitution + column IFFT (3-phase, h2 LDS) ----------
__global__ __launch_bounds__(512, 8) void k_col_ifft(h2* __restrict__ Fh, ull fh_cs,
                                                     const float* __restrict__ A, ull a_cs){
  __shared__ h2 sld[512*17];
  const int b    = blockIdx.x/17;
  const int tile = blockIdx.x - b*17;
  const int w0   = tile*16;
  const int cc   = blockIdx.y;
  h2* base = Fh + (size_t)cc*fh_cs + (size_t)b*HH*W2 + w0;
  const float* Aa = A + (size_t)cc*a_cs + w0;
  const int c = threadIdx.x&15, w = threadIdx.x>>4;
  const float invN2 = 1.0f/262144.0f;
#pragma unroll
  for(int jj=0;jj<2;jj++){                      // phase A: scale + inverse stage 2, from global
    int m = jj*32+w;
    float xr[8], xi[8];
#pragma unroll
    for(int q=0;q<8;q++){
      int p=8*m+q;
      float2 v = __half22float2(base[(size_t)p*W2+c]);
      float amp = Aa[(size_t)p*W2+c];
      float m2 = v.x*v.x + v.y*v.y;
      float sc = amp*invN2*__frsqrt_rn(m2);
      if(m2 > 0.f){ xr[q]=v.x*sc; xi[q]=v.y*sc; }
      else        { xr[q]=amp*invN2; xi[q]=0.f; }   // angle(0)=0
    }
    dft8<1>(xr,xi);
#pragma unroll
    for(int i=0;i<8;i++){ int e=8*m+i; sld[e*17+c]=__float22half2_rn(make_float2(xr[i],xi[i])); }
  }
  __syncthreads();
#pragma unroll
  for(int jj=0;jj<2;jj++){                      // phase B: inverse stage 1 in LDS
    int m = jj*32 + w;
    int bb = m>>3, nn = m&7, bs = 64*bb+nn;
    float xr[8], xi[8];
#pragma unroll
    for(int q=0;q<8;q++){ int e=bs+8*q; float2 v=__half22float2(sld[e*17+c]); xr[q]=v.x; xi[q]=v.y; }
    twid<1>(xr,xi,nn,1.0f/64.0f);
    dft8<1>(xr,xi);
#pragma unroll
    for(int i=0;i<8;i++){ int e=bs+8*i; sld[e*17+c]=__float22half2_rn(make_float2(xr[i],xi[i])); }
  }
  __syncthreads();
#pragma unroll
  for(int jj=0;jj<2;jj++){                      // phase C: inverse stage 0 -> global (natural h)
    int n = jj*32+w;
    float xr[8], xi[8];
#pragma unroll
    for(int q=0;q<8;q++){ int e=n+64*q; float2 v=__half22float2(sld[e*17+c]); xr[q]=v.x; xi[q]=v.y; }
    twid<1>(xr,xi,n,1.0f/512.0f);
    dft8<1>(xr,xi);
    if(w0+c<=256){
#pragma unroll
      for(int i=0;i<8;i++){ base[(size_t)(n+64*i)*W2+c]=__float22half2_rn(make_float2(xr[i],xi[i])); }
    }
  }
}

// ---------- K6: paired-row inverse real FFT (128 threads = 2 waves) ----------
// Post-column-inverse rows are Hermitian along w: Y[h,512-w]=conj(Y[h,w]).
__global__ __launch_bounds__(128) void k_row_irfft(const h2* __restrict__ Fh, ull fh_cs,
                                                   float* __restrict__ out){
  __shared__ h2 gA[2][264], gB[2][264];
  __shared__ float lre[2][512], lim[2][512];
  const int wv=threadIdx.x>>6, t=threadIdx.x&63;
  const int pr = blockIdx.x*2+wv;               // b*256 + r2
  const int b = pr>>8, r2 = pr&255;
  const int cc = blockIdx.y;
  const h2* Rp = Fh + (size_t)cc*fh_cs + (size_t)(b*HH + 2*r2)*W2;
  const h2* Rq = Rp + W2;
#pragma unroll
  for(int j=0;j<5;j++){
    int w = t + 64*j;
    if(w<=256){ gA[wv][w]=Rp[w]; gB[wv][w]=Rq[w]; }
  }
  __syncthreads();
  // gather digit-reversed slots: slot 8t+i needs Z[rev9(8t+i)]
  float xr[8], xi[8];
#pragma unroll
  for(int i=0;i<8;i++){
    int w = rev9(8*t+i);
    float zr, zi;
    if(w<=256){
      float2 a = __half22float2(gA[wv][w]);
      float2 bb = __half22float2(gB[wv][w]);
      zr = a.x - bb.y; zi = a.y + bb.x;
    }else{
      int m = 512-w;   // row-wise Hermitian: Z[w] = conj(A[m]) + i*conj(B[m])
      float2 a = __half22float2(gA[wv][m]);
      float2 bb = __half22float2(gB[wv][m]);
      zr = a.x + bb.y; zi = bb.x - a.y;
    }
    xr[i]=zr; xi[i]=zi;
  }
  dft8<1>(xr,xi);                               // inverse of stage 2
#pragma unroll
  for(int i=0;i<8;i++){ int pp=swz(8*t+i); lre[wv][pp]=xr[i]; lim[wv][pp]=xi[i]; }
  __syncthreads();
  const int beta=t>>3, n1=t&7, base1=64*beta+n1;
#pragma unroll
  for(int qq=0;qq<8;qq++){ int pp=swz(base1+8*qq); xr[qq]=lre[wv][pp]; xi[qq]=lim[wv][pp]; }
  twid<1>(xr,xi,n1,1.0f/64.0f);
  dft8<1>(xr,xi);                               // inverse of stage 1
#pragma unroll
  for(int i=0;i<8;i++){ int pp=swz(base1+8*i); lre[wv][pp]=xr[i]; lim[wv][pp]=xi[i]; }
  __syncthreads();
#pragma unroll
  for(int qq=0;qq<8;qq++){ int pp=swz(t+64*qq); xr[qq]=lre[wv][pp]; xi[qq]=lim[wv][pp]; }
  twid<1>(xr,xi,t,1.0f/512.0f);
  dft8<1>(xr,xi);                               // inverse of stage 0 -> natural w
  float* oa = out + (size_t)b*(NC*HH*WW) + (size_t)cc*HH*WW + (size_t)(2*r2)*WW;
  float* ob = oa + WW;
#pragma unroll
  for(int i=0;i<8;i++){ oa[t+64*i]=xr[i]; ob[t+64*i]=xi[i]; }
}

// ---------- launch ----------
extern "C" void kernel_launch(void* const* d_in, const int* in_sizes, int n_in,
                              void* d_out, int out_size, void* d_ws, size_t ws_size,
                              hipStream_t stream) {
  const float* x  = (const float*)d_in[0];        // [32,3,512,512]
  const float* ra = (const float*)d_in[1];        // [3,512,512]
  float* out = (float*)d_out;

  const ull fh_cs = (ull)NB*HH*W2;                 // half2 elems / channel
  const ull a_cs  = (ull)HH*W2;                    // floats / channel
  const size_t fb3 = (size_t)fh_cs*sizeof(h2)*3;   // 53.5 MB
  const size_t ab1 = (size_t)a_cs*sizeof(float);   // 0.56 MB
  // layout: [Fh (3ch, half2)] [rsum (64B)] [A (3ch)]
  const size_t need = fb3 + 64 + 3*ab1;
  if (ws_size < need) return;

  h2*    Fh   = (h2*)d_ws;
  float* rsum = (float*)((char*)d_ws + fb3);
  float* A    = (float*)((char*)rsum + 64);

  hipMemsetAsync(rsum, 0, sizeof(float), stream);
  k_rsum<<<768,256,0,stream>>>(ra, rsum, NC*HH*WW);

  k_row_rfft <<<dim3(NB*256/2,3), 128, 0, stream>>>(x, Fh, fh_cs);
  k_col_fft  <<<dim3(NB*17,3),    512, 0, stream>>>(Fh, fh_cs);
  k_amp      <<<dim3(HH*136/256,3),256, 0, stream>>>(Fh, fh_cs, ra, rsum, A, a_cs);
  k_col_ifft <<<dim3(NB*17,3),    512, 0, stream>>>(Fh, fh_cs, A, a_cs);
  k_row_irfft<<<dim3(NB*256/2,3), 128, 0, stream>>>(Fh, fh_cs, out);
}